// Round 1
// baseline (536.378 us; speedup 1.0000x reference)
//
#include <hip/hip_runtime.h>
#include <hip/hip_bf16.h>
#include <math.h>

#define B_ 32
#define S_ 2048
#define D_ 1024
#define TEMP_ 9.0f

typedef __attribute__((ext_vector_type(8))) short short8;
typedef __attribute__((ext_vector_type(4))) float f32x4;

__device__ __forceinline__ unsigned short f2b(float f) {
  union { float f; unsigned int u; } v; v.f = f;
  unsigned int r = v.u;
  r += 0x7fffu + ((r >> 16) & 1u);   // RNE
  return (unsigned short)(r >> 16);
}

// ---------------- K0: tdot[b] = h_t[b]·Wm_t + bmap ----------------
__global__ void k0_tdot(const float* __restrict__ h_t, const float* __restrict__ Wmap,
                        const float* __restrict__ bmap, float* __restrict__ tdot) {
  int b = blockIdx.x;
  int t = threadIdx.x;
  float p = 0.f;
  for (int k = t; k < D_; k += 256) p += h_t[b*D_ + k] * Wmap[D_ + k];
  __shared__ float red[256];
  red[t] = p; __syncthreads();
  for (int off = 128; off > 0; off >>= 1) { if (t < off) red[t] += red[t+off]; __syncthreads(); }
  if (t == 0) tdot[b] = red[0] + bmap[0];
}

// ---------------- K1: G[b,s] = sigmoid((aux·Wm_a + tdot[b] + logistic(u))/T) ----------------
__global__ void k1_gate(const float* __restrict__ aux, const float* __restrict__ Wmap,
                        const float* __restrict__ noise, const float* __restrict__ tdot,
                        float* __restrict__ Gout) {
  int w = (blockIdx.x * 256 + threadIdx.x) >> 6;  // global wave = row index b*S+s
  int lane = threadIdx.x & 63;
  const float4* arow = reinterpret_cast<const float4*>(aux + (size_t)w * D_);
  const float4* wrow = reinterpret_cast<const float4*>(Wmap);
  float p = 0.f;
  for (int it = 0; it < 4; ++it) {
    float4 a = arow[it*64 + lane];
    float4 m = wrow[it*64 + lane];
    p += a.x*m.x + a.y*m.y + a.z*m.z + a.w*m.w;
  }
  for (int msk = 32; msk > 0; msk >>= 1) p += __shfl_xor(p, msk);
  if (lane == 0) {
    int b = w >> 11;
    float logits = p + tdot[b];
    float u = noise[w];
    u = fminf(fmaxf(u, 1e-7f), 1.f - 1e-7f);
    float logistic = logf(u) - log1pf(-u);
    float x = (logits + logistic) / TEMP_;
    Gout[w] = 1.f / (1.f + expf(-x));
  }
}

// ---------------- K2: e[b,s] = sum_e tanh(h_s·W1[e,:] + b1[e]) * W2[e]  (bf16 MFMA) ----------------
#define BM 128
#define BN 128
#define BK 64

__global__ __launch_bounds__(256) void k2_egemm(
    const float* __restrict__ h_s, const float* __restrict__ W1,
    const float* __restrict__ b1, const float* __restrict__ W2,
    float* __restrict__ e_buf) {
  __shared__ unsigned short As[BM * BK];  // XOR-swizzled, rows of 64 bf16 = 128B
  __shared__ unsigned short Bs[BN * BK];
  int bid = blockIdx.x;
  int colBase = (bid & 7) * BN;       // col-chunk fastest -> 8 consecutive blocks share A panel in L2
  int rowBase = (bid >> 3) * BM;
  int t = threadIdx.x;
  int lane = t & 63;
  int wave = t >> 6;
  int wr = wave >> 1, wc = wave & 1;

  f32x4 acc[4][4] = {};

  for (int k0 = 0; k0 < D_; k0 += BK) {
    __syncthreads();
    // stage A (h_s, f32->bf16) and B (W1, f32->bf16), 128x64 each
    for (int i = 0; i < 4; ++i) {
      int flat = i*256 + t;          // 1024 chunks of 8 floats
      int r = flat >> 3;
      int c8 = flat & 7;
      int byte = (r*128 + c8*16) ^ ((r & 7) << 4);
      {
        const float4* g = reinterpret_cast<const float4*>(h_s + (size_t)(rowBase + r)*D_ + k0 + c8*8);
        float4 x0 = g[0], x1 = g[1];
        uint4 w;
        w.x = f2b(x0.x) | ((unsigned)f2b(x0.y) << 16);
        w.y = f2b(x0.z) | ((unsigned)f2b(x0.w) << 16);
        w.z = f2b(x1.x) | ((unsigned)f2b(x1.y) << 16);
        w.w = f2b(x1.z) | ((unsigned)f2b(x1.w) << 16);
        *reinterpret_cast<uint4*>(reinterpret_cast<char*>(As) + byte) = w;
      }
      {
        const float4* g = reinterpret_cast<const float4*>(W1 + (size_t)(colBase + r)*D_ + k0 + c8*8);
        float4 x0 = g[0], x1 = g[1];
        uint4 w;
        w.x = f2b(x0.x) | ((unsigned)f2b(x0.y) << 16);
        w.y = f2b(x0.z) | ((unsigned)f2b(x0.w) << 16);
        w.z = f2b(x1.x) | ((unsigned)f2b(x1.y) << 16);
        w.w = f2b(x1.z) | ((unsigned)f2b(x1.w) << 16);
        *reinterpret_cast<uint4*>(reinterpret_cast<char*>(Bs) + byte) = w;
      }
    }
    __syncthreads();
    for (int kk = 0; kk < BK; kk += 32) {
      short8 af[4], bf[4];
      int kByte = kk*2 + ((lane >> 4) << 4);
      for (int m = 0; m < 4; ++m) {
        int r = wr*64 + m*16 + (lane & 15);
        int byte = (r*128 + kByte) ^ ((r & 7) << 4);
        af[m] = *reinterpret_cast<const short8*>(reinterpret_cast<const char*>(As) + byte);
      }
      for (int n = 0; n < 4; ++n) {
        int r = wc*64 + n*16 + (lane & 15);
        int byte = (r*128 + kByte) ^ ((r & 7) << 4);
        bf[n] = *reinterpret_cast<const short8*>(reinterpret_cast<const char*>(Bs) + byte);
      }
      for (int m = 0; m < 4; ++m)
        for (int n = 0; n < 4; ++n)
          acc[m][n] = __builtin_amdgcn_mfma_f32_16x16x32_bf16(af[m], bf[n], acc[m][n], 0, 0, 0);
    }
  }

  // epilogue: e-partial = sum_cols tanh(pre + b1)*W2, reduce 16 lanes, atomicAdd per row
  float b1v[4], w2v[4];
  for (int n = 0; n < 4; ++n) {
    int col = colBase + wc*64 + n*16 + (lane & 15);
    b1v[n] = b1[col];
    w2v[n] = W2[col];
  }
  for (int m = 0; m < 4; ++m) {
    for (int j = 0; j < 4; ++j) {
      float s = 0.f;
      for (int n = 0; n < 4; ++n)
        s += tanhf(acc[m][n][j] + b1v[n]) * w2v[n];
      s += __shfl_xor(s, 1);
      s += __shfl_xor(s, 2);
      s += __shfl_xor(s, 4);
      s += __shfl_xor(s, 8);
      if ((lane & 15) == 0) {
        int row = rowBase + wr*64 + m*16 + ((lane >> 4) << 2) + j;
        atomicAdd(&e_buf[row], s);
      }
    }
  }
}

// ---------------- K3a: v[s] = max_b e[b,s] ----------------
__global__ void k3a_vmax(const float* __restrict__ e_buf, float* __restrict__ v) {
  int s = blockIdx.x * 256 + threadIdx.x;
  if (s >= S_) return;
  float m = -1e30f;
  for (int b = 0; b < B_; ++b) m = fmaxf(m, e_buf[b*S_ + s]);
  v[s] = m;
}

// ---------------- K3b: align = exp(e-v)*G / sum_s (in-place over G) ----------------
__global__ void k3b_align(const float* __restrict__ e_buf, const float* __restrict__ v,
                          float* __restrict__ galign) {
  int b = blockIdx.x;
  int t = threadIdx.x;
  __shared__ float sc[S_];
  __shared__ float red[256];
  float p = 0.f;
  for (int s = t; s < S_; s += 256) {
    float x = expf(e_buf[b*S_ + s] - v[s]) * galign[b*S_ + s];
    sc[s] = x;
    p += x;
  }
  red[t] = p; __syncthreads();
  for (int off = 128; off > 0; off >>= 1) { if (t < off) red[t] += red[t+off]; __syncthreads(); }
  float inv = 1.f / red[0];
  for (int s = t; s < S_; s += 256) galign[b*S_ + s] = sc[s] * inv;
}

// ---------------- K4: c[b,:] = sum_s align[b,s]*h_s[b,s,:] ----------------
__global__ void k4_ctx(const float* __restrict__ h_s, const float* __restrict__ align,
                       float* __restrict__ c) {
  int bid = blockIdx.x;
  int b = bid >> 6;
  int sBase = (bid & 63) * 32;
  int t = threadIdx.x;
  float4 accv = {0.f, 0.f, 0.f, 0.f};
  for (int si = 0; si < 32; ++si) {
    int s = sBase + si;
    float a = align[b*S_ + s];
    float4 hv = *reinterpret_cast<const float4*>(h_s + (size_t)(b*S_ + s)*D_ + t*4);
    accv.x += a*hv.x; accv.y += a*hv.y; accv.z += a*hv.z; accv.w += a*hv.w;
  }
  atomicAdd(&c[b*D_ + t*4 + 0], accv.x);
  atomicAdd(&c[b*D_ + t*4 + 1], accv.y);
  atomicAdd(&c[b*D_ + t*4 + 2], accv.z);
  atomicAdd(&c[b*D_ + t*4 + 3], accv.w);
}

// ---------------- K5: attn_h = tanh([c,h_t] @ Wout^T) ----------------
__global__ void k5_out(const float* __restrict__ c, const float* __restrict__ h_t,
                       const float* __restrict__ Wout, float* __restrict__ out) {
  int W = (blockIdx.x * 256 + threadIdx.x) >> 6;
  int lane = threadIdx.x & 63;
  int b = W >> 10;
  int o = W & 1023;
  const float* wrow = Wout + (size_t)o * (2 * D_);
  float p = 0.f;
  for (int it = 0; it < 16; ++it) {
    int k = it*64 + lane;
    p += c[b*D_ + k] * wrow[k];
  }
  for (int it = 16; it < 32; ++it) {
    int k = it*64 + lane;
    p += h_t[b*D_ + (k - D_)] * wrow[k];
  }
  for (int m = 32; m > 0; m >>= 1) p += __shfl_xor(p, m);
  if (lane == 0) out[b*D_ + o] = tanhf(p);
}

extern "C" void kernel_launch(void* const* d_in, const int* in_sizes, int n_in,
                              void* d_out, int out_size, void* d_ws, size_t ws_size,
                              hipStream_t stream) {
  const float* h_t   = (const float*)d_in[0];
  const float* h_s   = (const float*)d_in[1];
  const float* aux   = (const float*)d_in[2];
  const float* noise = (const float*)d_in[3];
  const float* Wmap  = (const float*)d_in[4];
  const float* bmap  = (const float*)d_in[5];
  const float* W1    = (const float*)d_in[6];
  const float* b1    = (const float*)d_in[7];
  const float* W2    = (const float*)d_in[8];
  // d_in[9] = b2: cancels exactly in exp(e-v)/sum -> unused
  const float* Wout  = (const float*)d_in[10];

  float* out    = (float*)d_out;          // [attn_h: 32768 | align: 65536]
  float* galign = out + B_*D_;            // holds G first, overwritten with align

  float* ws    = (float*)d_ws;
  float* e_buf = ws;                      // 65536
  float* tdot  = ws + 65536;              // 32
  float* v     = ws + 65568;              // 2048
  float* c     = ws + 67616;              // 32768  (total ~392 KB)

  hipMemsetAsync(e_buf, 0, 65536 * sizeof(float), stream);
  hipMemsetAsync(c, 0, 32768 * sizeof(float), stream);

  k0_tdot<<<32, 256, 0, stream>>>(h_t, Wmap, bmap, tdot);
  k1_gate<<<16384, 256, 0, stream>>>(aux, Wmap, noise, tdot, galign);
  k2_egemm<<<4096, 256, 0, stream>>>(h_s, W1, b1, W2, e_buf);
  k3a_vmax<<<8, 256, 0, stream>>>(e_buf, v);
  k3b_align<<<32, 256, 0, stream>>>(e_buf, v, galign);
  k4_ctx<<<2048, 256, 0, stream>>>(h_s, galign, c);
  k5_out<<<8192, 256, 0, stream>>>(c, h_t, Wout, out);
}

// Round 2
// 482.483 us; speedup vs baseline: 1.1117x; 1.1117x over previous
//
#include <hip/hip_runtime.h>
#include <hip/hip_bf16.h>
#include <math.h>

#define B_ 32
#define S_ 2048
#define D_ 1024
#define TEMP_ 9.0f

typedef __attribute__((ext_vector_type(8))) short short8;
typedef __attribute__((ext_vector_type(4))) float f32x4;
typedef __attribute__((ext_vector_type(4))) unsigned short ushort4v;

__device__ __forceinline__ unsigned short f2b(float f) {
  union { float f; unsigned int u; } v; v.f = f;
  unsigned int r = v.u;
  r += 0x7fffu + ((r >> 16) & 1u);   // RNE
  return (unsigned short)(r >> 16);
}
__device__ __forceinline__ float b2f(unsigned short b) {
  union { float f; unsigned int u; } v; v.u = ((unsigned int)b) << 16;
  return v.f;
}

#define GLOAD_LDS16(g, l) \
  __builtin_amdgcn_global_load_lds((const __attribute__((address_space(1))) void*)(g), \
                                   (__attribute__((address_space(3))) void*)(l), 16, 0, 0)

// ---------------- K_conv: f32 -> bf16, 8 elements/thread ----------------
__global__ void k_conv(const float* __restrict__ src, unsigned short* __restrict__ dst, int n8) {
  int i = blockIdx.x * 256 + threadIdx.x;
  if (i >= n8) return;
  const float4* g = reinterpret_cast<const float4*>(src) + (size_t)i * 2;
  float4 x0 = g[0], x1 = g[1];
  uint4 w;
  w.x = f2b(x0.x) | ((unsigned)f2b(x0.y) << 16);
  w.y = f2b(x0.z) | ((unsigned)f2b(x0.w) << 16);
  w.z = f2b(x1.x) | ((unsigned)f2b(x1.y) << 16);
  w.w = f2b(x1.z) | ((unsigned)f2b(x1.w) << 16);
  reinterpret_cast<uint4*>(dst)[i] = w;
}

// ---------------- K0: tdot[b] = h_t[b]·Wm_t + bmap ----------------
__global__ void k0_tdot(const float* __restrict__ h_t, const float* __restrict__ Wmap,
                        const float* __restrict__ bmap, float* __restrict__ tdot) {
  int b = blockIdx.x;
  int t = threadIdx.x;
  float p = 0.f;
  for (int k = t; k < D_; k += 256) p += h_t[b*D_ + k] * Wmap[D_ + k];
  __shared__ float red[256];
  red[t] = p; __syncthreads();
  for (int off = 128; off > 0; off >>= 1) { if (t < off) red[t] += red[t+off]; __syncthreads(); }
  if (t == 0) tdot[b] = red[0] + bmap[0];
}

// ---------------- K1: G[b,s] = sigmoid((aux·Wm_a + tdot[b] + logistic(u))/T) ----------------
__global__ void k1_gate(const float* __restrict__ aux, const float* __restrict__ Wmap,
                        const float* __restrict__ noise, const float* __restrict__ tdot,
                        float* __restrict__ Gout) {
  int w = (blockIdx.x * 256 + threadIdx.x) >> 6;  // global wave = row index b*S+s
  int lane = threadIdx.x & 63;
  const float4* arow = reinterpret_cast<const float4*>(aux + (size_t)w * D_);
  const float4* wrow = reinterpret_cast<const float4*>(Wmap);
  float p = 0.f;
  for (int it = 0; it < 4; ++it) {
    float4 a = arow[it*64 + lane];
    float4 m = wrow[it*64 + lane];
    p += a.x*m.x + a.y*m.y + a.z*m.z + a.w*m.w;
  }
  for (int msk = 32; msk > 0; msk >>= 1) p += __shfl_xor(p, msk);
  if (lane == 0) {
    int b = w >> 11;
    float logits = p + tdot[b];
    float u = noise[w];
    u = fminf(fmaxf(u, 1e-7f), 1.f - 1e-7f);
    float logistic = logf(u) - log1pf(-u);
    float x = (logits + logistic) / TEMP_;
    Gout[w] = 1.f / (1.f + expf(-x));
  }
}

// ---------------- K2 (bf16, m97 structure): e[b,s] = sum_e tanh(h_s·W1[e,:]+b1[e])*W2[e] ----------------
#define BM 128
#define BN 128
#define BK 64

__global__ __launch_bounds__(256) void k2_egemm_bf16(
    const unsigned short* __restrict__ A, const unsigned short* __restrict__ Bm,
    const float* __restrict__ b1, const float* __restrict__ W2,
    float* __restrict__ e_buf) {
  __shared__ unsigned short As[BM * BK];  // linear [128][64] bf16, 128B rows
  __shared__ unsigned short Bs[BN * BK];
  int bid = blockIdx.x;
  int colBase = (bid & 7) * BN;
  int rowBase = (bid >> 3) * BM;
  int t = threadIdx.x;
  int lane = t & 63;
  int wave = t >> 6;
  int wr = wave >> 1, wc = wave & 1;

  f32x4 acc[4][4] = {};

  for (int k0 = 0; k0 < D_; k0 += BK) {
    __syncthreads();
    // stage A and B: 1024 chunks of 16B each, LDS dest linear (wave-uniform base + lane*16)
    for (int i = 0; i < 4; ++i) {
      int c = i*256 + t;
      int r = c >> 3, c8 = c & 7;
      const unsigned short* g = A + (size_t)(rowBase + r)*D_ + k0 + c8*8;
      GLOAD_LDS16(g, (char*)As + c*16);
    }
    for (int i = 0; i < 4; ++i) {
      int c = i*256 + t;
      int r = c >> 3, c8 = c & 7;
      const unsigned short* g = Bm + (size_t)(colBase + r)*D_ + k0 + c8*8;
      GLOAD_LDS16(g, (char*)Bs + c*16);
    }
    __syncthreads();
    for (int kk = 0; kk < BK; kk += 32) {
      short8 af[4], bf[4];
      int kByte = (kk + ((lane >> 4) << 3)) * 2;
      for (int m = 0; m < 4; ++m) {
        int r = wr*64 + m*16 + (lane & 15);
        af[m] = *reinterpret_cast<const short8*>(reinterpret_cast<const char*>(As) + r*128 + kByte);
      }
      for (int n = 0; n < 4; ++n) {
        int r = wc*64 + n*16 + (lane & 15);
        bf[n] = *reinterpret_cast<const short8*>(reinterpret_cast<const char*>(Bs) + r*128 + kByte);
      }
      for (int m = 0; m < 4; ++m)
        for (int n = 0; n < 4; ++n)
          acc[m][n] = __builtin_amdgcn_mfma_f32_16x16x32_bf16(af[m], bf[n], acc[m][n], 0, 0, 0);
    }
  }

  // epilogue: e-partial = sum_cols tanh(pre + b1)*W2, reduce 16 lanes, atomicAdd per row
  float b1v[4], w2v[4];
  for (int n = 0; n < 4; ++n) {
    int col = colBase + wc*64 + n*16 + (lane & 15);
    b1v[n] = b1[col];
    w2v[n] = W2[col];
  }
  for (int m = 0; m < 4; ++m) {
    for (int j = 0; j < 4; ++j) {
      float s = 0.f;
      for (int n = 0; n < 4; ++n)
        s += tanhf(acc[m][n][j] + b1v[n]) * w2v[n];
      s += __shfl_xor(s, 1);
      s += __shfl_xor(s, 2);
      s += __shfl_xor(s, 4);
      s += __shfl_xor(s, 8);
      if ((lane & 15) == 0) {
        int row = rowBase + wr*64 + m*16 + ((lane >> 4) << 2) + j;
        atomicAdd(&e_buf[row], s);
      }
    }
  }
}

// ---------------- K2 fallback (f32 inputs, reg-staged conversion) ----------------
__global__ __launch_bounds__(256) void k2_egemm_f32(
    const float* __restrict__ h_s, const float* __restrict__ W1,
    const float* __restrict__ b1, const float* __restrict__ W2,
    float* __restrict__ e_buf) {
  __shared__ unsigned short As[BM * BK];
  __shared__ unsigned short Bs[BN * BK];
  int bid = blockIdx.x;
  int colBase = (bid & 7) * BN;
  int rowBase = (bid >> 3) * BM;
  int t = threadIdx.x;
  int lane = t & 63;
  int wave = t >> 6;
  int wr = wave >> 1, wc = wave & 1;
  f32x4 acc[4][4] = {};
  for (int k0 = 0; k0 < D_; k0 += BK) {
    __syncthreads();
    for (int i = 0; i < 4; ++i) {
      int flat = i*256 + t;
      int r = flat >> 3;
      int c8 = flat & 7;
      int byte = (r*128 + c8*16) ^ ((r & 7) << 4);
      {
        const float4* g = reinterpret_cast<const float4*>(h_s + (size_t)(rowBase + r)*D_ + k0 + c8*8);
        float4 x0 = g[0], x1 = g[1];
        uint4 w;
        w.x = f2b(x0.x) | ((unsigned)f2b(x0.y) << 16);
        w.y = f2b(x0.z) | ((unsigned)f2b(x0.w) << 16);
        w.z = f2b(x1.x) | ((unsigned)f2b(x1.y) << 16);
        w.w = f2b(x1.z) | ((unsigned)f2b(x1.w) << 16);
        *reinterpret_cast<uint4*>(reinterpret_cast<char*>(As) + byte) = w;
      }
      {
        const float4* g = reinterpret_cast<const float4*>(W1 + (size_t)(colBase + r)*D_ + k0 + c8*8);
        float4 x0 = g[0], x1 = g[1];
        uint4 w;
        w.x = f2b(x0.x) | ((unsigned)f2b(x0.y) << 16);
        w.y = f2b(x0.z) | ((unsigned)f2b(x0.w) << 16);
        w.z = f2b(x1.x) | ((unsigned)f2b(x1.y) << 16);
        w.w = f2b(x1.z) | ((unsigned)f2b(x1.w) << 16);
        *reinterpret_cast<uint4*>(reinterpret_cast<char*>(Bs) + byte) = w;
      }
    }
    __syncthreads();
    for (int kk = 0; kk < BK; kk += 32) {
      short8 af[4], bf[4];
      int kByte = kk*2 + ((lane >> 4) << 4);
      for (int m = 0; m < 4; ++m) {
        int r = wr*64 + m*16 + (lane & 15);
        int byte = (r*128 + kByte) ^ ((r & 7) << 4);
        af[m] = *reinterpret_cast<const short8*>(reinterpret_cast<const char*>(As) + byte);
      }
      for (int n = 0; n < 4; ++n) {
        int r = wc*64 + n*16 + (lane & 15);
        int byte = (r*128 + kByte) ^ ((r & 7) << 4);
        bf[n] = *reinterpret_cast<const short8*>(reinterpret_cast<const char*>(Bs) + byte);
      }
      for (int m = 0; m < 4; ++m)
        for (int n = 0; n < 4; ++n)
          acc[m][n] = __builtin_amdgcn_mfma_f32_16x16x32_bf16(af[m], bf[n], acc[m][n], 0, 0, 0);
    }
  }
  float b1v[4], w2v[4];
  for (int n = 0; n < 4; ++n) {
    int col = colBase + wc*64 + n*16 + (lane & 15);
    b1v[n] = b1[col];
    w2v[n] = W2[col];
  }
  for (int m = 0; m < 4; ++m) {
    for (int j = 0; j < 4; ++j) {
      float s = 0.f;
      for (int n = 0; n < 4; ++n)
        s += tanhf(acc[m][n][j] + b1v[n]) * w2v[n];
      s += __shfl_xor(s, 1);
      s += __shfl_xor(s, 2);
      s += __shfl_xor(s, 4);
      s += __shfl_xor(s, 8);
      if ((lane & 15) == 0) {
        int row = rowBase + wr*64 + m*16 + ((lane >> 4) << 2) + j;
        atomicAdd(&e_buf[row], s);
      }
    }
  }
}

// ---------------- K3a: v[s] = max_b e[b,s] ----------------
__global__ void k3a_vmax(const float* __restrict__ e_buf, float* __restrict__ v) {
  int s = blockIdx.x * 256 + threadIdx.x;
  if (s >= S_) return;
  float m = -1e30f;
  for (int b = 0; b < B_; ++b) m = fmaxf(m, e_buf[b*S_ + s]);
  v[s] = m;
}

// ---------------- K3b: align = exp(e-v)*G / sum_s (in-place over G) ----------------
__global__ void k3b_align(const float* __restrict__ e_buf, const float* __restrict__ v,
                          float* __restrict__ galign) {
  int b = blockIdx.x;
  int t = threadIdx.x;
  __shared__ float sc[S_];
  __shared__ float red[256];
  float p = 0.f;
  for (int s = t; s < S_; s += 256) {
    float x = expf(e_buf[b*S_ + s] - v[s]) * galign[b*S_ + s];
    sc[s] = x;
    p += x;
  }
  red[t] = p; __syncthreads();
  for (int off = 128; off > 0; off >>= 1) { if (t < off) red[t] += red[t+off]; __syncthreads(); }
  float inv = 1.f / red[0];
  for (int s = t; s < S_; s += 256) galign[b*S_ + s] = sc[s] * inv;
}

// ---------------- K4 (bf16 h_s): c[b,:] = sum_s align[b,s]*h_s[b,s,:] ----------------
__global__ void k4_ctx_bf16(const unsigned short* __restrict__ hsb, const float* __restrict__ align,
                            float* __restrict__ c) {
  int bid = blockIdx.x;
  int b = bid >> 6;
  int sBase = (bid & 63) * 32;
  int t = threadIdx.x;
  float4 accv = {0.f, 0.f, 0.f, 0.f};
  for (int si = 0; si < 32; ++si) {
    int s = sBase + si;
    float a = align[b*S_ + s];
    ushort4v hv = *reinterpret_cast<const ushort4v*>(hsb + (size_t)(b*S_ + s)*D_ + t*4);
    accv.x += a*b2f(hv.x); accv.y += a*b2f(hv.y); accv.z += a*b2f(hv.z); accv.w += a*b2f(hv.w);
  }
  atomicAdd(&c[b*D_ + t*4 + 0], accv.x);
  atomicAdd(&c[b*D_ + t*4 + 1], accv.y);
  atomicAdd(&c[b*D_ + t*4 + 2], accv.z);
  atomicAdd(&c[b*D_ + t*4 + 3], accv.w);
}

// ---------------- K4 fallback (f32 h_s) ----------------
__global__ void k4_ctx_f32(const float* __restrict__ h_s, const float* __restrict__ align,
                           float* __restrict__ c) {
  int bid = blockIdx.x;
  int b = bid >> 6;
  int sBase = (bid & 63) * 32;
  int t = threadIdx.x;
  float4 accv = {0.f, 0.f, 0.f, 0.f};
  for (int si = 0; si < 32; ++si) {
    int s = sBase + si;
    float a = align[b*S_ + s];
    float4 hv = *reinterpret_cast<const float4*>(h_s + (size_t)(b*S_ + s)*D_ + t*4);
    accv.x += a*hv.x; accv.y += a*hv.y; accv.z += a*hv.z; accv.w += a*hv.w;
  }
  atomicAdd(&c[b*D_ + t*4 + 0], accv.x);
  atomicAdd(&c[b*D_ + t*4 + 1], accv.y);
  atomicAdd(&c[b*D_ + t*4 + 2], accv.z);
  atomicAdd(&c[b*D_ + t*4 + 3], accv.w);
}

// ---------------- K5: attn_h = tanh([c,h_t] @ Wout^T) ----------------
__global__ void k5_out(const float* __restrict__ c, const float* __restrict__ h_t,
                       const float* __restrict__ Wout, float* __restrict__ out) {
  int W = (blockIdx.x * 256 + threadIdx.x) >> 6;
  int lane = threadIdx.x & 63;
  int b = W >> 10;
  int o = W & 1023;
  const float* wrow = Wout + (size_t)o * (2 * D_);
  float p = 0.f;
  for (int it = 0; it < 16; ++it) {
    int k = it*64 + lane;
    p += c[b*D_ + k] * wrow[k];
  }
  for (int it = 16; it < 32; ++it) {
    int k = it*64 + lane;
    p += h_t[b*D_ + (k - D_)] * wrow[k];
  }
  for (int m = 32; m > 0; m >>= 1) p += __shfl_xor(p, m);
  if (lane == 0) out[b*D_ + o] = tanhf(p);
}

extern "C" void kernel_launch(void* const* d_in, const int* in_sizes, int n_in,
                              void* d_out, int out_size, void* d_ws, size_t ws_size,
                              hipStream_t stream) {
  const float* h_t   = (const float*)d_in[0];
  const float* h_s   = (const float*)d_in[1];
  const float* aux   = (const float*)d_in[2];
  const float* noise = (const float*)d_in[3];
  const float* Wmap  = (const float*)d_in[4];
  const float* bmap  = (const float*)d_in[5];
  const float* W1    = (const float*)d_in[6];
  const float* b1    = (const float*)d_in[7];
  const float* W2    = (const float*)d_in[8];
  // d_in[9] = b2: cancels exactly in exp(e-v)/sum -> unused
  const float* Wout  = (const float*)d_in[10];

  float* out    = (float*)d_out;          // [attn_h: 32768 | align: 65536]
  float* galign = out + B_*D_;            // holds G first, overwritten with align

  const size_t HS_N   = (size_t)B_*S_*D_;   // 64M
  const size_t W1_N   = (size_t)D_*D_;      // 1M
  const size_t needed = HS_N*2 + W1_N*2 + (65536 + 32 + 2048 + 32768) * sizeof(float);

  if (ws_size >= needed) {
    unsigned short* hs_bf = (unsigned short*)d_ws;                 // 128 MB
    unsigned short* w1_bf = hs_bf + HS_N;                          // 2 MB
    float* fws   = (float*)(w1_bf + W1_N);
    float* e_buf = fws;                     // 65536
    float* tdot  = fws + 65536;             // 32
    float* v     = fws + 65568;             // 2048
    float* c     = fws + 67616;             // 32768

    hipMemsetAsync(e_buf, 0, 65536 * sizeof(float), stream);
    hipMemsetAsync(c, 0, 32768 * sizeof(float), stream);

    k_conv<<<(int)(HS_N/8/256), 256, 0, stream>>>(h_s, hs_bf, (int)(HS_N/8));
    k_conv<<<(int)(W1_N/8/256), 256, 0, stream>>>(W1, w1_bf, (int)(W1_N/8));
    k0_tdot<<<32, 256, 0, stream>>>(h_t, Wmap, bmap, tdot);
    k1_gate<<<16384, 256, 0, stream>>>(aux, Wmap, noise, tdot, galign);
    k2_egemm_bf16<<<4096, 256, 0, stream>>>(hs_bf, w1_bf, b1, W2, e_buf);
    k3a_vmax<<<8, 256, 0, stream>>>(e_buf, v);
    k3b_align<<<32, 256, 0, stream>>>(e_buf, v, galign);
    k4_ctx_bf16<<<2048, 256, 0, stream>>>(hs_bf, galign, c);
    k5_out<<<8192, 256, 0, stream>>>(c, h_t, Wout, out);
  } else {
    float* ws    = (float*)d_ws;
    float* e_buf = ws;                      // 65536
    float* tdot  = ws + 65536;              // 32
    float* v     = ws + 65568;              // 2048
    float* c     = ws + 67616;              // 32768

    hipMemsetAsync(e_buf, 0, 65536 * sizeof(float), stream);
    hipMemsetAsync(c, 0, 32768 * sizeof(float), stream);

    k0_tdot<<<32, 256, 0, stream>>>(h_t, Wmap, bmap, tdot);
    k1_gate<<<16384, 256, 0, stream>>>(aux, Wmap, noise, tdot, galign);
    k2_egemm_f32<<<4096, 256, 0, stream>>>(h_s, W1, b1, W2, e_buf);
    k3a_vmax<<<8, 256, 0, stream>>>(e_buf, v);
    k3b_align<<<32, 256, 0, stream>>>(e_buf, v, galign);
    k4_ctx_f32<<<2048, 256, 0, stream>>>(h_s, galign, c);
    k5_out<<<8192, 256, 0, stream>>>(c, h_t, Wout, out);
  }
}

// Round 3
// 394.456 us; speedup vs baseline: 1.3598x; 1.2232x over previous
//
#include <hip/hip_runtime.h>
#include <hip/hip_bf16.h>
#include <math.h>

#define B_ 32
#define S_ 2048
#define D_ 1024
#define TEMP_ 9.0f

typedef __attribute__((ext_vector_type(8))) short short8;
typedef __attribute__((ext_vector_type(4))) float f32x4;
typedef __attribute__((ext_vector_type(4))) unsigned short ushort4v;

__device__ __forceinline__ unsigned short f2b(float f) {
  union { float f; unsigned int u; } v; v.f = f;
  unsigned int r = v.u;
  r += 0x7fffu + ((r >> 16) & 1u);   // RNE
  return (unsigned short)(r >> 16);
}
__device__ __forceinline__ float b2f(unsigned short b) {
  union { float f; unsigned int u; } v; v.u = ((unsigned int)b) << 16;
  return v.f;
}
// fast tanh: 1 - 2/(e^2x + 1); saturates correctly at +-inf, ~1e-6 rel err
__device__ __forceinline__ float tanh_fast(float x) {
  float ez = __expf(2.f * x);
  return 1.f - __fdividef(2.f, ez + 1.f);
}

#define GLOAD_LDS16(g, l) \
  __builtin_amdgcn_global_load_lds((const __attribute__((address_space(1))) void*)(g), \
                                   (__attribute__((address_space(3))) void*)(l), 16, 0, 0)

// ---------------- K_conv: f32 -> bf16, 8 elements/thread ----------------
__global__ void k_conv(const float* __restrict__ src, unsigned short* __restrict__ dst, int n8) {
  int i = blockIdx.x * 256 + threadIdx.x;
  if (i >= n8) return;
  const float4* g = reinterpret_cast<const float4*>(src) + (size_t)i * 2;
  float4 x0 = g[0], x1 = g[1];
  uint4 w;
  w.x = f2b(x0.x) | ((unsigned)f2b(x0.y) << 16);
  w.y = f2b(x0.z) | ((unsigned)f2b(x0.w) << 16);
  w.z = f2b(x1.x) | ((unsigned)f2b(x1.y) << 16);
  w.w = f2b(x1.z) | ((unsigned)f2b(x1.w) << 16);
  reinterpret_cast<uint4*>(dst)[i] = w;
}

// ---------------- K0: tdot[b] = h_t[b]·Wm_t + bmap ----------------
__global__ void k0_tdot(const float* __restrict__ h_t, const float* __restrict__ Wmap,
                        const float* __restrict__ bmap, float* __restrict__ tdot) {
  int b = blockIdx.x;
  int t = threadIdx.x;
  float p = 0.f;
  for (int k = t; k < D_; k += 256) p += h_t[b*D_ + k] * Wmap[D_ + k];
  __shared__ float red[256];
  red[t] = p; __syncthreads();
  for (int off = 128; off > 0; off >>= 1) { if (t < off) red[t] += red[t+off]; __syncthreads(); }
  if (t == 0) tdot[b] = red[0] + bmap[0];
}

// ---------------- K1: G[b,s] = sigmoid((aux·Wm_a + tdot[b] + logistic(u))/T) ----------------
__global__ void k1_gate(const float* __restrict__ aux, const float* __restrict__ Wmap,
                        const float* __restrict__ noise, const float* __restrict__ tdot,
                        float* __restrict__ Gout) {
  int w = (blockIdx.x * 256 + threadIdx.x) >> 6;  // global wave = row index b*S+s
  int lane = threadIdx.x & 63;
  const float4* arow = reinterpret_cast<const float4*>(aux + (size_t)w * D_);
  const float4* wrow = reinterpret_cast<const float4*>(Wmap);
  float p = 0.f;
  for (int it = 0; it < 4; ++it) {
    float4 a = arow[it*64 + lane];
    float4 m = wrow[it*64 + lane];
    p += a.x*m.x + a.y*m.y + a.z*m.z + a.w*m.w;
  }
  for (int msk = 32; msk > 0; msk >>= 1) p += __shfl_xor(p, msk);
  if (lane == 0) {
    int b = w >> 11;
    float logits = p + tdot[b];
    float u = noise[w];
    u = fminf(fmaxf(u, 1e-7f), 1.f - 1e-7f);
    float logistic = logf(u) - log1pf(-u);
    float x = (logits + logistic) / TEMP_;
    Gout[w] = 1.f / (1.f + expf(-x));
  }
}

// ---------------- K2: 256x256 tile, BK=64, double-buffered 2-phase, 8 waves ----------------
// e[row] = sum_col tanh(h_s·W1[col,:] + b1[col]) * W2[col]
#define BM2 256
#define BN2 256
#define BK2 64
#define NT2 (D_ / BK2)   // 16

extern __shared__ unsigned short lds2[];  // 2 bufs x (A 16384 + B 16384) ushort = 128 KiB

__global__ __launch_bounds__(512, 2) void k2_256(
    const unsigned short* __restrict__ A, const unsigned short* __restrict__ Bm,
    const float* __restrict__ b1, const float* __restrict__ W2,
    float* __restrict__ e_buf) {
  // T1 bijective XCD swizzle: logical (rc in [0,256), cc in [0,4)), hw%8 = XCD.
  // hw = (rc%8) + 8*(cc + 4*(rc/8)) -> all 4 cc of an rc on one XCD, consecutive.
  int hw = blockIdx.x;
  int xcd = hw & 7;
  int sub = hw >> 3;            // [0,128)
  int cc  = sub & 3;
  int rc  = xcd + 8 * (sub >> 2);
  int rowBase = rc * BM2;
  int colBase = cc * BN2;

  int t = threadIdx.x;
  int lane = t & 63;
  int wv = t >> 6;
  int wr = wv >> 2, wc = wv & 3;   // 2 x 4 wave grid; wave output 128 rows x 64 cols

  f32x4 acc[8][4] = {};

  // stage K-tile tt into buffer b (linear LDS dest, per-lane global src)
  auto stage = [&](int tt, int b) {
    unsigned short* Ad = lds2 + b * 32768;
    unsigned short* Bd = Ad + 16384;
    int k0 = tt * BK2;
#pragma unroll
    for (int i = 0; i < 4; ++i) {
      int c = i * 512 + t;            // [0,2048) chunks of 16B
      int r = c >> 3, c8 = c & 7;
      GLOAD_LDS16(A + (size_t)(rowBase + r) * D_ + k0 + c8 * 8, (char*)Ad + c * 16);
    }
#pragma unroll
    for (int i = 0; i < 4; ++i) {
      int c = i * 512 + t;
      int r = c >> 3, c8 = c & 7;
      GLOAD_LDS16(Bm + (size_t)(colBase + r) * D_ + k0 + c8 * 8, (char*)Bd + c * 16);
    }
  };

  int cur = 0;
  stage(0, 0);
  for (int tt = 0; tt < NT2; ++tt) {
    __syncthreads();                 // drains vmcnt(0): tile tt landed; prev reads done
    if (tt + 1 < NT2) stage(tt + 1, cur ^ 1);
    const unsigned short* Ab = lds2 + cur * 32768;
    const unsigned short* Bb = Ab + 16384;
#pragma unroll
    for (int kk = 0; kk < BK2; kk += 32) {
      short8 af[8], bf[4];
      int kByte = (kk + ((lane >> 4) << 3)) * 2;
#pragma unroll
      for (int m = 0; m < 8; ++m) {
        int r = wr * 128 + m * 16 + (lane & 15);
        af[m] = *reinterpret_cast<const short8*>(reinterpret_cast<const char*>(Ab) + r * 128 + kByte);
      }
#pragma unroll
      for (int n = 0; n < 4; ++n) {
        int r = wc * 64 + n * 16 + (lane & 15);
        bf[n] = *reinterpret_cast<const short8*>(reinterpret_cast<const char*>(Bb) + r * 128 + kByte);
      }
#pragma unroll
      for (int m = 0; m < 8; ++m)
#pragma unroll
        for (int n = 0; n < 4; ++n)
          acc[m][n] = __builtin_amdgcn_mfma_f32_16x16x32_bf16(af[m], bf[n], acc[m][n], 0, 0, 0);
    }
    cur ^= 1;
  }

  // epilogue: e-partial = sum over this block's 256 cols of tanh(pre+b1)*W2
  float b1v[4], w2v[4];
#pragma unroll
  for (int n = 0; n < 4; ++n) {
    int col = colBase + wc * 64 + n * 16 + (lane & 15);
    b1v[n] = b1[col];
    w2v[n] = W2[col];
  }
#pragma unroll
  for (int m = 0; m < 8; ++m) {
#pragma unroll
    for (int j = 0; j < 4; ++j) {
      float s = 0.f;
#pragma unroll
      for (int n = 0; n < 4; ++n)
        s += tanh_fast(acc[m][n][j] + b1v[n]) * w2v[n];
      s += __shfl_xor(s, 1);
      s += __shfl_xor(s, 2);
      s += __shfl_xor(s, 4);
      s += __shfl_xor(s, 8);
      if ((lane & 15) == 0) {
        int row = rowBase + wr * 128 + m * 16 + ((lane >> 4) << 2) + j;
        atomicAdd(&e_buf[row], s);
      }
    }
  }
}

// ---------------- K2 fallback (f32 inputs, reg-staged conversion, 128^2) ----------------
#define BM 128
#define BN 128
#define BK 64
__global__ __launch_bounds__(256) void k2_egemm_f32(
    const float* __restrict__ h_s, const float* __restrict__ W1,
    const float* __restrict__ b1, const float* __restrict__ W2,
    float* __restrict__ e_buf) {
  __shared__ unsigned short As[BM * BK];
  __shared__ unsigned short Bs[BN * BK];
  int bid = blockIdx.x;
  int colBase = (bid & 7) * BN;
  int rowBase = (bid >> 3) * BM;
  int t = threadIdx.x;
  int lane = t & 63;
  int wave = t >> 6;
  int wr = wave >> 1, wc = wave & 1;
  f32x4 acc[4][4] = {};
  for (int k0 = 0; k0 < D_; k0 += BK) {
    __syncthreads();
    for (int i = 0; i < 4; ++i) {
      int flat = i*256 + t;
      int r = flat >> 3;
      int c8 = flat & 7;
      int byte = (r*128 + c8*16) ^ ((r & 7) << 4);
      {
        const float4* g = reinterpret_cast<const float4*>(h_s + (size_t)(rowBase + r)*D_ + k0 + c8*8);
        float4 x0 = g[0], x1 = g[1];
        uint4 w;
        w.x = f2b(x0.x) | ((unsigned)f2b(x0.y) << 16);
        w.y = f2b(x0.z) | ((unsigned)f2b(x0.w) << 16);
        w.z = f2b(x1.x) | ((unsigned)f2b(x1.y) << 16);
        w.w = f2b(x1.z) | ((unsigned)f2b(x1.w) << 16);
        *reinterpret_cast<uint4*>(reinterpret_cast<char*>(As) + byte) = w;
      }
      {
        const float4* g = reinterpret_cast<const float4*>(W1 + (size_t)(colBase + r)*D_ + k0 + c8*8);
        float4 x0 = g[0], x1 = g[1];
        uint4 w;
        w.x = f2b(x0.x) | ((unsigned)f2b(x0.y) << 16);
        w.y = f2b(x0.z) | ((unsigned)f2b(x0.w) << 16);
        w.z = f2b(x1.x) | ((unsigned)f2b(x1.y) << 16);
        w.w = f2b(x1.z) | ((unsigned)f2b(x1.w) << 16);
        *reinterpret_cast<uint4*>(reinterpret_cast<char*>(Bs) + byte) = w;
      }
    }
    __syncthreads();
    for (int kk = 0; kk < BK; kk += 32) {
      short8 af[4], bf[4];
      int kByte = kk*2 + ((lane >> 4) << 4);
      for (int m = 0; m < 4; ++m) {
        int r = wr*64 + m*16 + (lane & 15);
        int byte = (r*128 + kByte) ^ ((r & 7) << 4);
        af[m] = *reinterpret_cast<const short8*>(reinterpret_cast<const char*>(As) + byte);
      }
      for (int n = 0; n < 4; ++n) {
        int r = wc*64 + n*16 + (lane & 15);
        int byte = (r*128 + kByte) ^ ((r & 7) << 4);
        bf[n] = *reinterpret_cast<const short8*>(reinterpret_cast<const char*>(Bs) + byte);
      }
      for (int m = 0; m < 4; ++m)
        for (int n = 0; n < 4; ++n)
          acc[m][n] = __builtin_amdgcn_mfma_f32_16x16x32_bf16(af[m], bf[n], acc[m][n], 0, 0, 0);
    }
  }
  float b1v[4], w2v[4];
  for (int n = 0; n < 4; ++n) {
    int col = colBase + wc*64 + n*16 + (lane & 15);
    b1v[n] = b1[col];
    w2v[n] = W2[col];
  }
  for (int m = 0; m < 4; ++m) {
    for (int j = 0; j < 4; ++j) {
      float s = 0.f;
      for (int n = 0; n < 4; ++n)
        s += tanhf(acc[m][n][j] + b1v[n]) * w2v[n];
      s += __shfl_xor(s, 1);
      s += __shfl_xor(s, 2);
      s += __shfl_xor(s, 4);
      s += __shfl_xor(s, 8);
      if ((lane & 15) == 0) {
        int row = rowBase + wr*64 + m*16 + ((lane >> 4) << 2) + j;
        atomicAdd(&e_buf[row], s);
      }
    }
  }
}

// ---------------- K3a: v[s] = max_b e[b,s] ----------------
__global__ void k3a_vmax(const float* __restrict__ e_buf, float* __restrict__ v) {
  int s = blockIdx.x * 256 + threadIdx.x;
  if (s >= S_) return;
  float m = -1e30f;
  for (int b = 0; b < B_; ++b) m = fmaxf(m, e_buf[b*S_ + s]);
  v[s] = m;
}

// ---------------- K3b: align = exp(e-v)*G / sum_s (in-place over G) ----------------
__global__ void k3b_align(const float* __restrict__ e_buf, const float* __restrict__ v,
                          float* __restrict__ galign) {
  int b = blockIdx.x;
  int t = threadIdx.x;
  __shared__ float sc[S_];
  __shared__ float red[256];
  float p = 0.f;
  for (int s = t; s < S_; s += 256) {
    float x = expf(e_buf[b*S_ + s] - v[s]) * galign[b*S_ + s];
    sc[s] = x;
    p += x;
  }
  red[t] = p; __syncthreads();
  for (int off = 128; off > 0; off >>= 1) { if (t < off) red[t] += red[t+off]; __syncthreads(); }
  float inv = 1.f / red[0];
  for (int s = t; s < S_; s += 256) galign[b*S_ + s] = sc[s] * inv;
}

// ---------------- K4 (bf16 h_s): c[b,:] = sum_s align[b,s]*h_s[b,s,:] ----------------
__global__ void k4_ctx_bf16(const unsigned short* __restrict__ hsb, const float* __restrict__ align,
                            float* __restrict__ c) {
  int bid = blockIdx.x;
  int b = bid >> 6;
  int sBase = (bid & 63) * 32;
  int t = threadIdx.x;
  float4 accv = {0.f, 0.f, 0.f, 0.f};
  for (int si = 0; si < 32; ++si) {
    int s = sBase + si;
    float a = align[b*S_ + s];
    ushort4v hv = *reinterpret_cast<const ushort4v*>(hsb + (size_t)(b*S_ + s)*D_ + t*4);
    accv.x += a*b2f(hv.x); accv.y += a*b2f(hv.y); accv.z += a*b2f(hv.z); accv.w += a*b2f(hv.w);
  }
  atomicAdd(&c[b*D_ + t*4 + 0], accv.x);
  atomicAdd(&c[b*D_ + t*4 + 1], accv.y);
  atomicAdd(&c[b*D_ + t*4 + 2], accv.z);
  atomicAdd(&c[b*D_ + t*4 + 3], accv.w);
}

// ---------------- K4 fallback (f32 h_s) ----------------
__global__ void k4_ctx_f32(const float* __restrict__ h_s, const float* __restrict__ align,
                           float* __restrict__ c) {
  int bid = blockIdx.x;
  int b = bid >> 6;
  int sBase = (bid & 63) * 32;
  int t = threadIdx.x;
  float4 accv = {0.f, 0.f, 0.f, 0.f};
  for (int si = 0; si < 32; ++si) {
    int s = sBase + si;
    float a = align[b*S_ + s];
    float4 hv = *reinterpret_cast<const float4*>(h_s + (size_t)(b*S_ + s)*D_ + t*4);
    accv.x += a*hv.x; accv.y += a*hv.y; accv.z += a*hv.z; accv.w += a*hv.w;
  }
  atomicAdd(&c[b*D_ + t*4 + 0], accv.x);
  atomicAdd(&c[b*D_ + t*4 + 1], accv.y);
  atomicAdd(&c[b*D_ + t*4 + 2], accv.z);
  atomicAdd(&c[b*D_ + t*4 + 3], accv.w);
}

// ---------------- K5: attn_h = tanh([c,h_t] @ Wout^T) ----------------
__global__ void k5_out(const float* __restrict__ c, const float* __restrict__ h_t,
                       const float* __restrict__ Wout, float* __restrict__ out) {
  int W = (blockIdx.x * 256 + threadIdx.x) >> 6;
  int lane = threadIdx.x & 63;
  int b = W >> 10;
  int o = W & 1023;
  const float* wrow = Wout + (size_t)o * (2 * D_);
  float p = 0.f;
  for (int it = 0; it < 16; ++it) {
    int k = it*64 + lane;
    p += c[b*D_ + k] * wrow[k];
  }
  for (int it = 16; it < 32; ++it) {
    int k = it*64 + lane;
    p += h_t[b*D_ + (k - D_)] * wrow[k];
  }
  for (int m = 32; m > 0; m >>= 1) p += __shfl_xor(p, m);
  if (lane == 0) out[b*D_ + o] = tanhf(p);
}

extern "C" void kernel_launch(void* const* d_in, const int* in_sizes, int n_in,
                              void* d_out, int out_size, void* d_ws, size_t ws_size,
                              hipStream_t stream) {
  const float* h_t   = (const float*)d_in[0];
  const float* h_s   = (const float*)d_in[1];
  const float* aux   = (const float*)d_in[2];
  const float* noise = (const float*)d_in[3];
  const float* Wmap  = (const float*)d_in[4];
  const float* bmap  = (const float*)d_in[5];
  const float* W1    = (const float*)d_in[6];
  const float* b1    = (const float*)d_in[7];
  const float* W2    = (const float*)d_in[8];
  // d_in[9] = b2: cancels exactly in exp(e-v)/sum -> unused
  const float* Wout  = (const float*)d_in[10];

  float* out    = (float*)d_out;          // [attn_h: 32768 | align: 65536]
  float* galign = out + B_*D_;            // holds G first, overwritten with align

  const size_t HS_N   = (size_t)B_*S_*D_;   // 64M
  const size_t W1_N   = (size_t)D_*D_;      // 1M
  const size_t needed = HS_N*2 + W1_N*2 + (65536 + 32 + 2048 + 32768) * sizeof(float);

  if (ws_size >= needed) {
    unsigned short* hs_bf = (unsigned short*)d_ws;                 // 128 MB
    unsigned short* w1_bf = hs_bf + HS_N;                          // 2 MB
    float* fws   = (float*)(w1_bf + W1_N);
    float* e_buf = fws;                     // 65536
    float* tdot  = fws + 65536;             // 32
    float* v     = fws + 65568;             // 2048
    float* c     = fws + 67616;             // 32768

    hipMemsetAsync(e_buf, 0, 65536 * sizeof(float), stream);
    hipMemsetAsync(c, 0, 32768 * sizeof(float), stream);

    hipFuncSetAttribute(reinterpret_cast<const void*>(k2_256),
                        hipFuncAttributeMaxDynamicSharedMemorySize, 131072);

    k_conv<<<(int)(HS_N/8/256), 256, 0, stream>>>(h_s, hs_bf, (int)(HS_N/8));
    k_conv<<<(int)(W1_N/8/256), 256, 0, stream>>>(W1, w1_bf, (int)(W1_N/8));
    k0_tdot<<<32, 256, 0, stream>>>(h_t, Wmap, bmap, tdot);
    k1_gate<<<16384, 256, 0, stream>>>(aux, Wmap, noise, tdot, galign);
    k2_256<<<1024, 512, 131072, stream>>>(hs_bf, w1_bf, b1, W2, e_buf);
    k3a_vmax<<<8, 256, 0, stream>>>(e_buf, v);
    k3b_align<<<32, 256, 0, stream>>>(e_buf, v, galign);
    k4_ctx_bf16<<<2048, 256, 0, stream>>>(hs_bf, galign, c);
    k5_out<<<8192, 256, 0, stream>>>(c, h_t, Wout, out);
  } else {
    float* ws    = (float*)d_ws;
    float* e_buf = ws;                      // 65536
    float* tdot  = ws + 65536;              // 32
    float* v     = ws + 65568;              // 2048
    float* c     = ws + 67616;              // 32768

    hipMemsetAsync(e_buf, 0, 65536 * sizeof(float), stream);
    hipMemsetAsync(c, 0, 32768 * sizeof(float), stream);

    k0_tdot<<<32, 256, 0, stream>>>(h_t, Wmap, bmap, tdot);
    k1_gate<<<16384, 256, 0, stream>>>(aux, Wmap, noise, tdot, galign);
    k2_egemm_f32<<<4096, 256, 0, stream>>>(h_s, W1, b1, W2, e_buf);
    k3a_vmax<<<8, 256, 0, stream>>>(e_buf, v);
    k3b_align<<<32, 256, 0, stream>>>(e_buf, v, galign);
    k4_ctx_f32<<<2048, 256, 0, stream>>>(h_s, galign, c);
    k5_out<<<8192, 256, 0, stream>>>(c, h_t, Wout, out);
  }
}

// Round 4
// 366.551 us; speedup vs baseline: 1.4633x; 1.0761x over previous
//
#include <hip/hip_runtime.h>
#include <hip/hip_bf16.h>
#include <math.h>

#define B_ 32
#define S_ 2048
#define D_ 1024
#define TEMP_ 9.0f

typedef __attribute__((ext_vector_type(8))) short short8;
typedef __attribute__((ext_vector_type(4))) float f32x4;
typedef __attribute__((ext_vector_type(4))) unsigned short ushort4v;

__device__ __forceinline__ unsigned short f2b(float f) {
  union { float f; unsigned int u; } v; v.f = f;
  unsigned int r = v.u;
  r += 0x7fffu + ((r >> 16) & 1u);   // RNE
  return (unsigned short)(r >> 16);
}
__device__ __forceinline__ float b2f(unsigned short b) {
  union { float f; unsigned int u; } v; v.u = ((unsigned int)b) << 16;
  return v.f;
}
// fast tanh: 1 - 2/(e^2x + 1); saturates correctly at +-inf
__device__ __forceinline__ float tanh_fast(float x) {
  float ez = __expf(2.f * x);
  return 1.f - __fdividef(2.f, ez + 1.f);
}

#define GLOAD_LDS16(g, l) \
  __builtin_amdgcn_global_load_lds((const __attribute__((address_space(1))) void*)(g), \
                                   (__attribute__((address_space(3))) void*)(l), 16, 0, 0)

// ---------------- K_conv: f32 -> bf16, 8 elements/thread ----------------
__global__ void k_conv(const float* __restrict__ src, unsigned short* __restrict__ dst, int n8) {
  int i = blockIdx.x * 256 + threadIdx.x;
  if (i >= n8) return;
  const float4* g = reinterpret_cast<const float4*>(src) + (size_t)i * 2;
  float4 x0 = g[0], x1 = g[1];
  uint4 w;
  w.x = f2b(x0.x) | ((unsigned)f2b(x0.y) << 16);
  w.y = f2b(x0.z) | ((unsigned)f2b(x0.w) << 16);
  w.z = f2b(x1.x) | ((unsigned)f2b(x1.y) << 16);
  w.w = f2b(x1.z) | ((unsigned)f2b(x1.w) << 16);
  reinterpret_cast<uint4*>(dst)[i] = w;
}

// ---------------- K0: tdot[b] = h_t[b]·Wm_t + bmap ----------------
__global__ void k0_tdot(const float* __restrict__ h_t, const float* __restrict__ Wmap,
                        const float* __restrict__ bmap, float* __restrict__ tdot) {
  int b = blockIdx.x;
  int t = threadIdx.x;
  float p = 0.f;
  for (int k = t; k < D_; k += 256) p += h_t[b*D_ + k] * Wmap[D_ + k];
  __shared__ float red[256];
  red[t] = p; __syncthreads();
  for (int off = 128; off > 0; off >>= 1) { if (t < off) red[t] += red[t+off]; __syncthreads(); }
  if (t == 0) tdot[b] = red[0] + bmap[0];
}

// ---------------- K1: G[b,s] = sigmoid((aux·Wm_a + tdot[b] + logistic(u))/T) ----------------
__global__ void k1_gate(const float* __restrict__ aux, const float* __restrict__ Wmap,
                        const float* __restrict__ noise, const float* __restrict__ tdot,
                        float* __restrict__ Gout) {
  int w = (blockIdx.x * 256 + threadIdx.x) >> 6;  // global wave = row index b*S+s
  int lane = threadIdx.x & 63;
  const float4* arow = reinterpret_cast<const float4*>(aux + (size_t)w * D_);
  const float4* wrow = reinterpret_cast<const float4*>(Wmap);
  float p = 0.f;
  for (int it = 0; it < 4; ++it) {
    float4 a = arow[it*64 + lane];
    float4 m = wrow[it*64 + lane];
    p += a.x*m.x + a.y*m.y + a.z*m.z + a.w*m.w;
  }
  for (int msk = 32; msk > 0; msk >>= 1) p += __shfl_xor(p, msk);
  if (lane == 0) {
    int b = w >> 11;
    float logits = p + tdot[b];
    float u = noise[w];
    u = fminf(fmaxf(u, 1e-7f), 1.f - 1e-7f);
    float logistic = logf(u) - log1pf(-u);
    float x = (logits + logistic) / TEMP_;
    Gout[w] = 1.f / (1.f + expf(-x));
  }
}

// ---------------- K2: 256x256 tile, BK=32, quad-buffered depth-3 pipeline ----------------
// e[row] = sum_col tanh(h_s·W1[col,:] + b1[col]) * W2[col]
#define BK3 32
#define NT3 (D_ / BK3)   // 32 K-tiles

extern __shared__ unsigned short lds2[];  // 4 bufs x (A 256x32 + B 256x32) ushort = 128 KiB

__global__ __launch_bounds__(512, 2) void k2_pipe(
    const unsigned short* __restrict__ Ag, const unsigned short* __restrict__ Bg,
    const float* __restrict__ b1, const float* __restrict__ W2,
    float* __restrict__ e_buf) {
  // T1 bijective XCD swizzle: all 4 col-chunks of a row-chunk on one XCD.
  int hw = blockIdx.x;
  int xcd = hw & 7;
  int sub = hw >> 3;            // [0,128)
  int cc  = sub & 3;
  int rc  = xcd + 8 * (sub >> 2);
  int rowBase = rc * 256;
  int colBase = cc * 256;

  int t = threadIdx.x;
  int lane = t & 63;
  int wv = t >> 6;
  int wr = wv >> 2, wc = wv & 3;   // 2 x 4 wave grid; wave output 128 rows x 64 cols
  int kOff = (lane >> 4) << 4;     // byte offset of lane's k-slot within a 64B row

  f32x4 acc[8][4] = {};

  // stage K-tile tt into buffer tt&3 (linear LDS, 16B chunks; 4 gload_lds/thread)
  auto stage = [&](int tt) {
    unsigned short* dstA = lds2 + (tt & 3) * 16384;
    unsigned short* dstB = dstA + 8192;
    int k0 = tt * BK3;
#pragma unroll
    for (int i = 0; i < 2; ++i) {
      int c = i * 512 + t;            // [0,1024) chunks of 16B; r = c/4, c4 = c%4
      int r = c >> 2, c4 = c & 3;
      GLOAD_LDS16(Ag + (size_t)(rowBase + r) * D_ + k0 + c4 * 8, (char*)dstA + c * 16);
    }
#pragma unroll
    for (int i = 0; i < 2; ++i) {
      int c = i * 512 + t;
      int r = c >> 2, c4 = c & 3;
      GLOAD_LDS16(Bg + (size_t)(colBase + r) * D_ + k0 + c4 * 8, (char*)dstB + c * 16);
    }
  };

  // Per-tile body. Invariants:
  //  - lgkmcnt(0) before barrier: this wave's ds_reads retired -> buffer (T+3)&3
  //    (read 2 tiles ago) is safe to overwrite after the barrier.
  //  - vmcnt(VM) before barrier: VM = 4 loads x tiles-newer-than-T -> tile T landed.
  //  - sched_barrier(0): no hoist of ds_reads above s_barrier.
#define K2_TILE(T, VM, DO_STAGE) do {                                          \
    asm volatile("s_waitcnt lgkmcnt(0)\n\ts_waitcnt vmcnt(" #VM ")" ::: "memory"); \
    __builtin_amdgcn_s_barrier();                                              \
    __builtin_amdgcn_sched_barrier(0);                                         \
    const unsigned short* Ab = lds2 + ((T) & 3) * 16384;                       \
    const unsigned short* Bb = Ab + 8192;                                      \
    short8 af[8], bf[4];                                                       \
    _Pragma("unroll")                                                          \
    for (int m = 0; m < 8; ++m) {                                              \
      int r = wr * 128 + m * 16 + (lane & 15);                                 \
      af[m] = *reinterpret_cast<const short8*>(                                \
          reinterpret_cast<const char*>(Ab) + r * 64 + kOff);                  \
    }                                                                          \
    _Pragma("unroll")                                                          \
    for (int n = 0; n < 4; ++n) {                                              \
      int r = wc * 64 + n * 16 + (lane & 15);                                  \
      bf[n] = *reinterpret_cast<const short8*>(                                \
          reinterpret_cast<const char*>(Bb) + r * 64 + kOff);                  \
    }                                                                          \
    if (DO_STAGE) stage((T) + 3);                                              \
    __builtin_amdgcn_s_setprio(1);                                             \
    _Pragma("unroll")                                                          \
    for (int m = 0; m < 8; ++m)                                                \
      _Pragma("unroll")                                                        \
      for (int n = 0; n < 4; ++n)                                              \
        acc[m][n] = __builtin_amdgcn_mfma_f32_16x16x32_bf16(af[m], bf[n], acc[m][n], 0, 0, 0); \
    __builtin_amdgcn_s_setprio(0);                                             \
  } while (0)

  stage(0); stage(1); stage(2);
  for (int tt = 0; tt <= NT3 - 4; ++tt) K2_TILE(tt, 8, true);
  K2_TILE(NT3 - 3, 8, false);
  K2_TILE(NT3 - 2, 4, false);
  K2_TILE(NT3 - 1, 0, false);
#undef K2_TILE

  // epilogue: e-partial = sum over this block's 256 cols of tanh(pre+b1)*W2
  float b1v[4], w2v[4];
#pragma unroll
  for (int n = 0; n < 4; ++n) {
    int col = colBase + wc * 64 + n * 16 + (lane & 15);
    b1v[n] = b1[col];
    w2v[n] = W2[col];
  }
#pragma unroll
  for (int m = 0; m < 8; ++m) {
#pragma unroll
    for (int j = 0; j < 4; ++j) {
      float s = 0.f;
#pragma unroll
      for (int n = 0; n < 4; ++n)
        s += tanh_fast(acc[m][n][j] + b1v[n]) * w2v[n];
      s += __shfl_xor(s, 1);
      s += __shfl_xor(s, 2);
      s += __shfl_xor(s, 4);
      s += __shfl_xor(s, 8);
      if ((lane & 15) == 0) {
        int row = rowBase + wr * 128 + m * 16 + ((lane >> 4) << 2) + j;
        atomicAdd(&e_buf[row], s);
      }
    }
  }
}

// ---------------- K2 fallback (f32 inputs, reg-staged conversion, 128^2) ----------------
#define BM 128
#define BN 128
#define BK 64
__global__ __launch_bounds__(256) void k2_egemm_f32(
    const float* __restrict__ h_s, const float* __restrict__ W1,
    const float* __restrict__ b1, const float* __restrict__ W2,
    float* __restrict__ e_buf) {
  __shared__ unsigned short As[BM * BK];
  __shared__ unsigned short Bs[BN * BK];
  int bid = blockIdx.x;
  int colBase = (bid & 7) * BN;
  int rowBase = (bid >> 3) * BM;
  int t = threadIdx.x;
  int lane = t & 63;
  int wave = t >> 6;
  int wr = wave >> 1, wc = wave & 1;
  f32x4 acc[4][4] = {};
  for (int k0 = 0; k0 < D_; k0 += BK) {
    __syncthreads();
    for (int i = 0; i < 4; ++i) {
      int flat = i*256 + t;
      int r = flat >> 3;
      int c8 = flat & 7;
      int byte = (r*128 + c8*16) ^ ((r & 7) << 4);
      {
        const float4* g = reinterpret_cast<const float4*>(h_s + (size_t)(rowBase + r)*D_ + k0 + c8*8);
        float4 x0 = g[0], x1 = g[1];
        uint4 w;
        w.x = f2b(x0.x) | ((unsigned)f2b(x0.y) << 16);
        w.y = f2b(x0.z) | ((unsigned)f2b(x0.w) << 16);
        w.z = f2b(x1.x) | ((unsigned)f2b(x1.y) << 16);
        w.w = f2b(x1.z) | ((unsigned)f2b(x1.w) << 16);
        *reinterpret_cast<uint4*>(reinterpret_cast<char*>(As) + byte) = w;
      }
      {
        const float4* g = reinterpret_cast<const float4*>(W1 + (size_t)(colBase + r)*D_ + k0 + c8*8);
        float4 x0 = g[0], x1 = g[1];
        uint4 w;
        w.x = f2b(x0.x) | ((unsigned)f2b(x0.y) << 16);
        w.y = f2b(x0.z) | ((unsigned)f2b(x0.w) << 16);
        w.z = f2b(x1.x) | ((unsigned)f2b(x1.y) << 16);
        w.w = f2b(x1.z) | ((unsigned)f2b(x1.w) << 16);
        *reinterpret_cast<uint4*>(reinterpret_cast<char*>(Bs) + byte) = w;
      }
    }
    __syncthreads();
    for (int kk = 0; kk < BK; kk += 32) {
      short8 af[4], bf[4];
      int kByte = kk*2 + ((lane >> 4) << 4);
      for (int m = 0; m < 4; ++m) {
        int r = wr*64 + m*16 + (lane & 15);
        int byte = (r*128 + kByte) ^ ((r & 7) << 4);
        af[m] = *reinterpret_cast<const short8*>(reinterpret_cast<const char*>(As) + byte);
      }
      for (int n = 0; n < 4; ++n) {
        int r = wc*64 + n*16 + (lane & 15);
        int byte = (r*128 + kByte) ^ ((r & 7) << 4);
        bf[n] = *reinterpret_cast<const short8*>(reinterpret_cast<const char*>(Bs) + byte);
      }
      for (int m = 0; m < 4; ++m)
        for (int n = 0; n < 4; ++n)
          acc[m][n] = __builtin_amdgcn_mfma_f32_16x16x32_bf16(af[m], bf[n], acc[m][n], 0, 0, 0);
    }
  }
  float b1v[4], w2v[4];
  for (int n = 0; n < 4; ++n) {
    int col = colBase + wc*64 + n*16 + (lane & 15);
    b1v[n] = b1[col];
    w2v[n] = W2[col];
  }
  for (int m = 0; m < 4; ++m) {
    for (int j = 0; j < 4; ++j) {
      float s = 0.f;
      for (int n = 0; n < 4; ++n)
        s += tanhf(acc[m][n][j] + b1v[n]) * w2v[n];
      s += __shfl_xor(s, 1);
      s += __shfl_xor(s, 2);
      s += __shfl_xor(s, 4);
      s += __shfl_xor(s, 8);
      if ((lane & 15) == 0) {
        int row = rowBase + wr*64 + m*16 + ((lane >> 4) << 2) + j;
        atomicAdd(&e_buf[row], s);
      }
    }
  }
}

// ---------------- K3a: v[s] = max_b e[b,s] ----------------
__global__ void k3a_vmax(const float* __restrict__ e_buf, float* __restrict__ v) {
  int s = blockIdx.x * 256 + threadIdx.x;
  if (s >= S_) return;
  float m = -1e30f;
  for (int b = 0; b < B_; ++b) m = fmaxf(m, e_buf[b*S_ + s]);
  v[s] = m;
}

// ---------------- K3b: align = exp(e-v)*G / sum_s (in-place over G) ----------------
__global__ void k3b_align(const float* __restrict__ e_buf, const float* __restrict__ v,
                          float* __restrict__ galign) {
  int b = blockIdx.x;
  int t = threadIdx.x;
  __shared__ float sc[S_];
  __shared__ float red[256];
  float p = 0.f;
  for (int s = t; s < S_; s += 256) {
    float x = expf(e_buf[b*S_ + s] - v[s]) * galign[b*S_ + s];
    sc[s] = x;
    p += x;
  }
  red[t] = p; __syncthreads();
  for (int off = 128; off > 0; off >>= 1) { if (t < off) red[t] += red[t+off]; __syncthreads(); }
  float inv = 1.f / red[0];
  for (int s = t; s < S_; s += 256) galign[b*S_ + s] = sc[s] * inv;
}

// ---------------- K4 (bf16 h_s): c[b,:] = sum_s align[b,s]*h_s[b,s,:] ----------------
__global__ void k4_ctx_bf16(const unsigned short* __restrict__ hsb, const float* __restrict__ align,
                            float* __restrict__ c) {
  int bid = blockIdx.x;
  int b = bid >> 6;
  int sBase = (bid & 63) * 32;
  int t = threadIdx.x;
  float4 accv = {0.f, 0.f, 0.f, 0.f};
  for (int si = 0; si < 32; ++si) {
    int s = sBase + si;
    float a = align[b*S_ + s];
    ushort4v hv = *reinterpret_cast<const ushort4v*>(hsb + (size_t)(b*S_ + s)*D_ + t*4);
    accv.x += a*b2f(hv.x); accv.y += a*b2f(hv.y); accv.z += a*b2f(hv.z); accv.w += a*b2f(hv.w);
  }
  atomicAdd(&c[b*D_ + t*4 + 0], accv.x);
  atomicAdd(&c[b*D_ + t*4 + 1], accv.y);
  atomicAdd(&c[b*D_ + t*4 + 2], accv.z);
  atomicAdd(&c[b*D_ + t*4 + 3], accv.w);
}

// ---------------- K4 fallback (f32 h_s) ----------------
__global__ void k4_ctx_f32(const float* __restrict__ h_s, const float* __restrict__ align,
                           float* __restrict__ c) {
  int bid = blockIdx.x;
  int b = bid >> 6;
  int sBase = (bid & 63) * 32;
  int t = threadIdx.x;
  float4 accv = {0.f, 0.f, 0.f, 0.f};
  for (int si = 0; si < 32; ++si) {
    int s = sBase + si;
    float a = align[b*S_ + s];
    float4 hv = *reinterpret_cast<const float4*>(h_s + (size_t)(b*S_ + s)*D_ + t*4);
    accv.x += a*hv.x; accv.y += a*hv.y; accv.z += a*hv.z; accv.w += a*hv.w;
  }
  atomicAdd(&c[b*D_ + t*4 + 0], accv.x);
  atomicAdd(&c[b*D_ + t*4 + 1], accv.y);
  atomicAdd(&c[b*D_ + t*4 + 2], accv.z);
  atomicAdd(&c[b*D_ + t*4 + 3], accv.w);
}

// ---------------- K5: attn_h = tanh([c,h_t] @ Wout^T) ----------------
__global__ void k5_out(const float* __restrict__ c, const float* __restrict__ h_t,
                       const float* __restrict__ Wout, float* __restrict__ out) {
  int W = (blockIdx.x * 256 + threadIdx.x) >> 6;
  int lane = threadIdx.x & 63;
  int b = W >> 10;
  int o = W & 1023;
  const float* wrow = Wout + (size_t)o * (2 * D_);
  float p = 0.f;
  for (int it = 0; it < 16; ++it) {
    int k = it*64 + lane;
    p += c[b*D_ + k] * wrow[k];
  }
  for (int it = 16; it < 32; ++it) {
    int k = it*64 + lane;
    p += h_t[b*D_ + (k - D_)] * wrow[k];
  }
  for (int m = 32; m > 0; m >>= 1) p += __shfl_xor(p, m);
  if (lane == 0) out[b*D_ + o] = tanhf(p);
}

extern "C" void kernel_launch(void* const* d_in, const int* in_sizes, int n_in,
                              void* d_out, int out_size, void* d_ws, size_t ws_size,
                              hipStream_t stream) {
  const float* h_t   = (const float*)d_in[0];
  const float* h_s   = (const float*)d_in[1];
  const float* aux   = (const float*)d_in[2];
  const float* noise = (const float*)d_in[3];
  const float* Wmap  = (const float*)d_in[4];
  const float* bmap  = (const float*)d_in[5];
  const float* W1    = (const float*)d_in[6];
  const float* b1    = (const float*)d_in[7];
  const float* W2    = (const float*)d_in[8];
  // d_in[9] = b2: cancels exactly in exp(e-v)/sum -> unused
  const float* Wout  = (const float*)d_in[10];

  float* out    = (float*)d_out;          // [attn_h: 32768 | align: 65536]
  float* galign = out + B_*D_;            // holds G first, overwritten with align

  const size_t HS_N   = (size_t)B_*S_*D_;   // 64M
  const size_t W1_N   = (size_t)D_*D_;      // 1M
  const size_t needed = HS_N*2 + W1_N*2 + (65536 + 32 + 2048 + 32768) * sizeof(float);

  if (ws_size >= needed) {
    unsigned short* hs_bf = (unsigned short*)d_ws;                 // 128 MB
    unsigned short* w1_bf = hs_bf + HS_N;                          // 2 MB
    float* fws   = (float*)(w1_bf + W1_N);
    float* e_buf = fws;                     // 65536
    float* tdot  = fws + 65536;             // 32
    float* v     = fws + 65568;             // 2048
    float* c     = fws + 67616;             // 32768

    hipMemsetAsync(e_buf, 0, 65536 * sizeof(float), stream);
    hipMemsetAsync(c, 0, 32768 * sizeof(float), stream);

    hipFuncSetAttribute(reinterpret_cast<const void*>(k2_pipe),
                        hipFuncAttributeMaxDynamicSharedMemorySize, 131072);

    k_conv<<<(int)(HS_N/8/256), 256, 0, stream>>>(h_s, hs_bf, (int)(HS_N/8));
    k_conv<<<(int)(W1_N/8/256), 256, 0, stream>>>(W1, w1_bf, (int)(W1_N/8));
    k0_tdot<<<32, 256, 0, stream>>>(h_t, Wmap, bmap, tdot);
    k1_gate<<<16384, 256, 0, stream>>>(aux, Wmap, noise, tdot, galign);
    k2_pipe<<<1024, 512, 131072, stream>>>(hs_bf, w1_bf, b1, W2, e_buf);
    k3a_vmax<<<8, 256, 0, stream>>>(e_buf, v);
    k3b_align<<<32, 256, 0, stream>>>(e_buf, v, galign);
    k4_ctx_bf16<<<2048, 256, 0, stream>>>(hs_bf, galign, c);
    k5_out<<<8192, 256, 0, stream>>>(c, h_t, Wout, out);
  } else {
    float* ws    = (float*)d_ws;
    float* e_buf = ws;                      // 65536
    float* tdot  = ws + 65536;              // 32
    float* v     = ws + 65568;              // 2048
    float* c     = ws + 67616;              // 32768

    hipMemsetAsync(e_buf, 0, 65536 * sizeof(float), stream);
    hipMemsetAsync(c, 0, 32768 * sizeof(float), stream);

    k0_tdot<<<32, 256, 0, stream>>>(h_t, Wmap, bmap, tdot);
    k1_gate<<<16384, 256, 0, stream>>>(aux, Wmap, noise, tdot, galign);
    k2_egemm_f32<<<4096, 256, 0, stream>>>(h_s, W1, b1, W2, e_buf);
    k3a_vmax<<<8, 256, 0, stream>>>(e_buf, v);
    k3b_align<<<32, 256, 0, stream>>>(e_buf, v, galign);
    k4_ctx_f32<<<2048, 256, 0, stream>>>(h_s, galign, c);
    k5_out<<<8192, 256, 0, stream>>>(c, h_t, Wout, out);
  }
}

// Round 5
// 364.740 us; speedup vs baseline: 1.4706x; 1.0050x over previous
//
#include <hip/hip_runtime.h>
#include <hip/hip_bf16.h>
#include <math.h>

#define B_ 32
#define S_ 2048
#define D_ 1024
#define TEMP_ 9.0f

typedef __attribute__((ext_vector_type(8))) short short8;
typedef __attribute__((ext_vector_type(4))) float f32x4;
typedef __attribute__((ext_vector_type(4))) unsigned short ushort4v;

__device__ __forceinline__ unsigned short f2b(float f) {
  union { float f; unsigned int u; } v; v.f = f;
  unsigned int r = v.u;
  r += 0x7fffu + ((r >> 16) & 1u);   // RNE
  return (unsigned short)(r >> 16);
}
__device__ __forceinline__ float b2f(unsigned short b) {
  union { float f; unsigned int u; } v; v.u = ((unsigned int)b) << 16;
  return v.f;
}
// fast tanh: 1 - 2/(e^2x + 1); saturates correctly at +-inf
__device__ __forceinline__ float tanh_fast(float x) {
  float ez = __expf(2.f * x);
  return 1.f - __fdividef(2.f, ez + 1.f);
}

#define GLOAD_LDS16(g, l) \
  __builtin_amdgcn_global_load_lds((const __attribute__((address_space(1))) void*)(g), \
                                   (__attribute__((address_space(3))) void*)(l), 16, 0, 0)

// ---------------- K_conv: f32 -> bf16, 8 elements/thread ----------------
__global__ void k_conv(const float* __restrict__ src, unsigned short* __restrict__ dst, int n8) {
  int i = blockIdx.x * 256 + threadIdx.x;
  if (i >= n8) return;
  const float4* g = reinterpret_cast<const float4*>(src) + (size_t)i * 2;
  float4 x0 = g[0], x1 = g[1];
  uint4 w;
  w.x = f2b(x0.x) | ((unsigned)f2b(x0.y) << 16);
  w.y = f2b(x0.z) | ((unsigned)f2b(x0.w) << 16);
  w.z = f2b(x1.x) | ((unsigned)f2b(x1.y) << 16);
  w.w = f2b(x1.z) | ((unsigned)f2b(x1.w) << 16);
  reinterpret_cast<uint4*>(dst)[i] = w;
}

// ---------------- K0: tdot[b] = h_t[b]·Wm_t + bmap ----------------
__global__ void k0_tdot(const float* __restrict__ h_t, const float* __restrict__ Wmap,
                        const float* __restrict__ bmap, float* __restrict__ tdot) {
  int b = blockIdx.x;
  int t = threadIdx.x;
  float p = 0.f;
  for (int k = t; k < D_; k += 256) p += h_t[b*D_ + k] * Wmap[D_ + k];
  __shared__ float red[256];
  red[t] = p; __syncthreads();
  for (int off = 128; off > 0; off >>= 1) { if (t < off) red[t] += red[t+off]; __syncthreads(); }
  if (t == 0) tdot[b] = red[0] + bmap[0];
}

// ---------------- K1: G[b,s] = sigmoid((aux·Wm_a + tdot[b] + logistic(u))/T) ----------------
__global__ void k1_gate(const float* __restrict__ aux, const float* __restrict__ Wmap,
                        const float* __restrict__ noise, const float* __restrict__ tdot,
                        float* __restrict__ Gout) {
  int w = (blockIdx.x * 256 + threadIdx.x) >> 6;  // global wave = row index b*S+s
  int lane = threadIdx.x & 63;
  const float4* arow = reinterpret_cast<const float4*>(aux + (size_t)w * D_);
  const float4* wrow = reinterpret_cast<const float4*>(Wmap);
  float p = 0.f;
  for (int it = 0; it < 4; ++it) {
    float4 a = arow[it*64 + lane];
    float4 m = wrow[it*64 + lane];
    p += a.x*m.x + a.y*m.y + a.z*m.z + a.w*m.w;
  }
  for (int msk = 32; msk > 0; msk >>= 1) p += __shfl_xor(p, msk);
  if (lane == 0) {
    int b = w >> 11;
    float logits = p + tdot[b];
    float u = noise[w];
    u = fminf(fmaxf(u, 1e-7f), 1.f - 1e-7f);
    float logistic = logf(u) - log1pf(-u);
    float x = (logits + logistic) / TEMP_;
    Gout[w] = 1.f / (1.f + expf(-x));
  }
}

// ---------------- K2: 256x256 tile, BK=32, quad-buffered depth-3 pipeline, T2 swizzle ----------------
// e[row] = sum_col tanh(h_s·W1[col,:] + b1[col]) * W2[col]
// LDS swizzle (T2, both-sides involution): 64B rows, 4 slots of 16B;
// physical slot = logical slot ^ ((r>>1)&3). Spreads 16-lane fragment reads
// across all 8 four-bank groups (half = r&1, group = slot) -> 2-way max.
#define BK3 32
#define NT3 (D_ / BK3)   // 32 K-tiles

extern __shared__ unsigned short lds2[];  // 4 bufs x (A 256x32 + B 256x32) ushort = 128 KiB

__global__ __launch_bounds__(512, 2) void k2_pipe(
    const unsigned short* __restrict__ Ag, const unsigned short* __restrict__ Bg,
    const float* __restrict__ b1, const float* __restrict__ W2,
    float* __restrict__ e_buf) {
  // T1 bijective XCD swizzle: all 4 col-chunks of a row-chunk on one XCD.
  int hw = blockIdx.x;
  int xcd = hw & 7;
  int sub = hw >> 3;            // [0,128)
  int cc  = sub & 3;
  int rc  = xcd + 8 * (sub >> 2);
  int rowBase = rc * 256;
  int colBase = cc * 256;

  int t = threadIdx.x;
  int lane = t & 63;
  int wv = t >> 6;
  int wr = wv >> 2, wc = wv & 3;   // 2 x 4 wave grid; wave output 128 rows x 64 cols
  int kslot = lane >> 4;           // lane's logical 16B k-slot within a 64B row

  f32x4 acc[8][4] = {};

  // stage K-tile tt into buffer tt&3. LDS dest linear (gload_lds requirement);
  // swizzle realized by permuting the per-lane GLOBAL source chunk.
  auto stage = [&](int tt) {
    unsigned short* dstA = lds2 + (tt & 3) * 16384;
    unsigned short* dstB = dstA + 8192;
    int k0 = tt * BK3;
#pragma unroll
    for (int i = 0; i < 2; ++i) {
      int c = i * 512 + t;            // physical chunk [0,1024): r = c/4, slot = c%4
      int r = c >> 2;
      int clog = (c & 3) ^ ((r >> 1) & 3);
      GLOAD_LDS16(Ag + (size_t)(rowBase + r) * D_ + k0 + clog * 8, (char*)dstA + c * 16);
    }
#pragma unroll
    for (int i = 0; i < 2; ++i) {
      int c = i * 512 + t;
      int r = c >> 2;
      int clog = (c & 3) ^ ((r >> 1) & 3);
      GLOAD_LDS16(Bg + (size_t)(colBase + r) * D_ + k0 + clog * 8, (char*)dstB + c * 16);
    }
  };

  // Per-tile body. Invariants:
  //  - lgkmcnt(0) before barrier: this wave's ds_reads retired -> buffer (T+3)&3
  //    (read 2 tiles ago) is safe to overwrite after the barrier.
  //  - vmcnt(VM) before barrier: VM = 4 loads x tiles-newer-than-T -> tile T landed.
  //  - sched_barrier(0): no hoist of ds_reads above s_barrier.
#define K2_TILE(T, VM, DO_STAGE) do {                                          \
    asm volatile("s_waitcnt lgkmcnt(0)\n\ts_waitcnt vmcnt(" #VM ")" ::: "memory"); \
    __builtin_amdgcn_s_barrier();                                              \
    __builtin_amdgcn_sched_barrier(0);                                         \
    const unsigned short* Ab = lds2 + ((T) & 3) * 16384;                       \
    const unsigned short* Bb = Ab + 8192;                                      \
    short8 af[8], bf[4];                                                       \
    _Pragma("unroll")                                                          \
    for (int m = 0; m < 8; ++m) {                                              \
      int r = wr * 128 + m * 16 + (lane & 15);                                 \
      int byte = r * 64 + ((kslot ^ ((r >> 1) & 3)) << 4);                     \
      af[m] = *reinterpret_cast<const short8*>(                                \
          reinterpret_cast<const char*>(Ab) + byte);                           \
    }                                                                          \
    _Pragma("unroll")                                                          \
    for (int n = 0; n < 4; ++n) {                                              \
      int r = wc * 64 + n * 16 + (lane & 15);                                  \
      int byte = r * 64 + ((kslot ^ ((r >> 1) & 3)) << 4);                     \
      bf[n] = *reinterpret_cast<const short8*>(                                \
          reinterpret_cast<const char*>(Bb) + byte);                           \
    }                                                                          \
    if (DO_STAGE) stage((T) + 3);                                              \
    __builtin_amdgcn_s_setprio(1);                                             \
    _Pragma("unroll")                                                          \
    for (int m = 0; m < 8; ++m)                                                \
      _Pragma("unroll")                                                        \
      for (int n = 0; n < 4; ++n)                                              \
        acc[m][n] = __builtin_amdgcn_mfma_f32_16x16x32_bf16(af[m], bf[n], acc[m][n], 0, 0, 0); \
    __builtin_amdgcn_s_setprio(0);                                             \
  } while (0)

  stage(0); stage(1); stage(2);
  for (int tt = 0; tt <= NT3 - 4; ++tt) K2_TILE(tt, 8, true);
  K2_TILE(NT3 - 3, 8, false);
  K2_TILE(NT3 - 2, 4, false);
  K2_TILE(NT3 - 1, 0, false);
#undef K2_TILE

  // epilogue: e-partial = sum over this block's 256 cols of tanh(pre+b1)*W2
  float b1v[4], w2v[4];
#pragma unroll
  for (int n = 0; n < 4; ++n) {
    int col = colBase + wc * 64 + n * 16 + (lane & 15);
    b1v[n] = b1[col];
    w2v[n] = W2[col];
  }
#pragma unroll
  for (int m = 0; m < 8; ++m) {
#pragma unroll
    for (int j = 0; j < 4; ++j) {
      float s = 0.f;
#pragma unroll
      for (int n = 0; n < 4; ++n)
        s += tanh_fast(acc[m][n][j] + b1v[n]) * w2v[n];
      s += __shfl_xor(s, 1);
      s += __shfl_xor(s, 2);
      s += __shfl_xor(s, 4);
      s += __shfl_xor(s, 8);
      if ((lane & 15) == 0) {
        int row = rowBase + wr * 128 + m * 16 + ((lane >> 4) << 2) + j;
        atomicAdd(&e_buf[row], s);
      }
    }
  }
}

// ---------------- K2 fallback (f32 inputs, reg-staged conversion, 128^2) ----------------
#define BM 128
#define BN 128
#define BK 64
__global__ __launch_bounds__(256) void k2_egemm_f32(
    const float* __restrict__ h_s, const float* __restrict__ W1,
    const float* __restrict__ b1, const float* __restrict__ W2,
    float* __restrict__ e_buf) {
  __shared__ unsigned short As[BM * BK];
  __shared__ unsigned short Bs[BN * BK];
  int bid = blockIdx.x;
  int colBase = (bid & 7) * BN;
  int rowBase = (bid >> 3) * BM;
  int t = threadIdx.x;
  int lane = t & 63;
  int wave = t >> 6;
  int wr = wave >> 1, wc = wave & 1;
  f32x4 acc[4][4] = {};
  for (int k0 = 0; k0 < D_; k0 += BK) {
    __syncthreads();
    for (int i = 0; i < 4; ++i) {
      int flat = i*256 + t;
      int r = flat >> 3;
      int c8 = flat & 7;
      int byte = (r*128 + c8*16) ^ ((r & 7) << 4);
      {
        const float4* g = reinterpret_cast<const float4*>(h_s + (size_t)(rowBase + r)*D_ + k0 + c8*8);
        float4 x0 = g[0], x1 = g[1];
        uint4 w;
        w.x = f2b(x0.x) | ((unsigned)f2b(x0.y) << 16);
        w.y = f2b(x0.z) | ((unsigned)f2b(x0.w) << 16);
        w.z = f2b(x1.x) | ((unsigned)f2b(x1.y) << 16);
        w.w = f2b(x1.z) | ((unsigned)f2b(x1.w) << 16);
        *reinterpret_cast<uint4*>(reinterpret_cast<char*>(As) + byte) = w;
      }
      {
        const float4* g = reinterpret_cast<const float4*>(W1 + (size_t)(colBase + r)*D_ + k0 + c8*8);
        float4 x0 = g[0], x1 = g[1];
        uint4 w;
        w.x = f2b(x0.x) | ((unsigned)f2b(x0.y) << 16);
        w.y = f2b(x0.z) | ((unsigned)f2b(x0.w) << 16);
        w.z = f2b(x1.x) | ((unsigned)f2b(x1.y) << 16);
        w.w = f2b(x1.z) | ((unsigned)f2b(x1.w) << 16);
        *reinterpret_cast<uint4*>(reinterpret_cast<char*>(Bs) + byte) = w;
      }
    }
    __syncthreads();
    for (int kk = 0; kk < BK; kk += 32) {
      short8 af[4], bf[4];
      int kByte = kk*2 + ((lane >> 4) << 4);
      for (int m = 0; m < 4; ++m) {
        int r = wr*64 + m*16 + (lane & 15);
        int byte = (r*128 + kByte) ^ ((r & 7) << 4);
        af[m] = *reinterpret_cast<const short8*>(reinterpret_cast<const char*>(As) + byte);
      }
      for (int n = 0; n < 4; ++n) {
        int r = wc*64 + n*16 + (lane & 15);
        int byte = (r*128 + kByte) ^ ((r & 7) << 4);
        bf[n] = *reinterpret_cast<const short8*>(reinterpret_cast<const char*>(Bs) + byte);
      }
      for (int m = 0; m < 4; ++m)
        for (int n = 0; n < 4; ++n)
          acc[m][n] = __builtin_amdgcn_mfma_f32_16x16x32_bf16(af[m], bf[n], acc[m][n], 0, 0, 0);
    }
  }
  float b1v[4], w2v[4];
  for (int n = 0; n < 4; ++n) {
    int col = colBase + wc*64 + n*16 + (lane & 15);
    b1v[n] = b1[col];
    w2v[n] = W2[col];
  }
  for (int m = 0; m < 4; ++m) {
    for (int j = 0; j < 4; ++j) {
      float s = 0.f;
      for (int n = 0; n < 4; ++n)
        s += tanhf(acc[m][n][j] + b1v[n]) * w2v[n];
      s += __shfl_xor(s, 1);
      s += __shfl_xor(s, 2);
      s += __shfl_xor(s, 4);
      s += __shfl_xor(s, 8);
      if ((lane & 15) == 0) {
        int row = rowBase + wr*64 + m*16 + ((lane >> 4) << 2) + j;
        atomicAdd(&e_buf[row], s);
      }
    }
  }
}

// ---------------- K3a: v[s] = max_b e[b,s] ----------------
__global__ void k3a_vmax(const float* __restrict__ e_buf, float* __restrict__ v) {
  int s = blockIdx.x * 256 + threadIdx.x;
  if (s >= S_) return;
  float m = -1e30f;
  for (int b = 0; b < B_; ++b) m = fmaxf(m, e_buf[b*S_ + s]);
  v[s] = m;
}

// ---------------- K3b: align = exp(e-v)*G / sum_s (in-place over G) ----------------
__global__ void k3b_align(const float* __restrict__ e_buf, const float* __restrict__ v,
                          float* __restrict__ galign) {
  int b = blockIdx.x;
  int t = threadIdx.x;
  __shared__ float sc[S_];
  __shared__ float red[256];
  float p = 0.f;
  for (int s = t; s < S_; s += 256) {
    float x = expf(e_buf[b*S_ + s] - v[s]) * galign[b*S_ + s];
    sc[s] = x;
    p += x;
  }
  red[t] = p; __syncthreads();
  for (int off = 128; off > 0; off >>= 1) { if (t < off) red[t] += red[t+off]; __syncthreads(); }
  float inv = 1.f / red[0];
  for (int s = t; s < S_; s += 256) galign[b*S_ + s] = sc[s] * inv;
}

// ---------------- K4 (bf16 h_s): c[b,:] = sum_s align[b,s]*h_s[b,s,:] ----------------
__global__ void k4_ctx_bf16(const unsigned short* __restrict__ hsb, const float* __restrict__ align,
                            float* __restrict__ c) {
  int bid = blockIdx.x;
  int b = bid >> 6;
  int sBase = (bid & 63) * 32;
  int t = threadIdx.x;
  float4 accv = {0.f, 0.f, 0.f, 0.f};
  for (int si = 0; si < 32; ++si) {
    int s = sBase + si;
    float a = align[b*S_ + s];
    ushort4v hv = *reinterpret_cast<const ushort4v*>(hsb + (size_t)(b*S_ + s)*D_ + t*4);
    accv.x += a*b2f(hv.x); accv.y += a*b2f(hv.y); accv.z += a*b2f(hv.z); accv.w += a*b2f(hv.w);
  }
  atomicAdd(&c[b*D_ + t*4 + 0], accv.x);
  atomicAdd(&c[b*D_ + t*4 + 1], accv.y);
  atomicAdd(&c[b*D_ + t*4 + 2], accv.z);
  atomicAdd(&c[b*D_ + t*4 + 3], accv.w);
}

// ---------------- K4 fallback (f32 h_s) ----------------
__global__ void k4_ctx_f32(const float* __restrict__ h_s, const float* __restrict__ align,
                           float* __restrict__ c) {
  int bid = blockIdx.x;
  int b = bid >> 6;
  int sBase = (bid & 63) * 32;
  int t = threadIdx.x;
  float4 accv = {0.f, 0.f, 0.f, 0.f};
  for (int si = 0; si < 32; ++si) {
    int s = sBase + si;
    float a = align[b*S_ + s];
    float4 hv = *reinterpret_cast<const float4*>(h_s + (size_t)(b*S_ + s)*D_ + t*4);
    accv.x += a*hv.x; accv.y += a*hv.y; accv.z += a*hv.z; accv.w += a*hv.w;
  }
  atomicAdd(&c[b*D_ + t*4 + 0], accv.x);
  atomicAdd(&c[b*D_ + t*4 + 1], accv.y);
  atomicAdd(&c[b*D_ + t*4 + 2], accv.z);
  atomicAdd(&c[b*D_ + t*4 + 3], accv.w);
}

// ---------------- K5: attn_h = tanh([c,h_t] @ Wout^T) ----------------
__global__ void k5_out(const float* __restrict__ c, const float* __restrict__ h_t,
                       const float* __restrict__ Wout, float* __restrict__ out) {
  int W = (blockIdx.x * 256 + threadIdx.x) >> 6;
  int lane = threadIdx.x & 63;
  int b = W >> 10;
  int o = W & 1023;
  const float* wrow = Wout + (size_t)o * (2 * D_);
  float p = 0.f;
  for (int it = 0; it < 16; ++it) {
    int k = it*64 + lane;
    p += c[b*D_ + k] * wrow[k];
  }
  for (int it = 16; it < 32; ++it) {
    int k = it*64 + lane;
    p += h_t[b*D_ + (k - D_)] * wrow[k];
  }
  for (int m = 32; m > 0; m >>= 1) p += __shfl_xor(p, m);
  if (lane == 0) out[b*D_ + o] = tanhf(p);
}

extern "C" void kernel_launch(void* const* d_in, const int* in_sizes, int n_in,
                              void* d_out, int out_size, void* d_ws, size_t ws_size,
                              hipStream_t stream) {
  const float* h_t   = (const float*)d_in[0];
  const float* h_s   = (const float*)d_in[1];
  const float* aux   = (const float*)d_in[2];
  const float* noise = (const float*)d_in[3];
  const float* Wmap  = (const float*)d_in[4];
  const float* bmap  = (const float*)d_in[5];
  const float* W1    = (const float*)d_in[6];
  const float* b1    = (const float*)d_in[7];
  const float* W2    = (const float*)d_in[8];
  // d_in[9] = b2: cancels exactly in exp(e-v)/sum -> unused
  const float* Wout  = (const float*)d_in[10];

  float* out    = (float*)d_out;          // [attn_h: 32768 | align: 65536]
  float* galign = out + B_*D_;            // holds G first, overwritten with align

  const size_t HS_N   = (size_t)B_*S_*D_;   // 64M
  const size_t W1_N   = (size_t)D_*D_;      // 1M
  const size_t needed = HS_N*2 + W1_N*2 + (65536 + 32 + 2048 + 32768) * sizeof(float);

  if (ws_size >= needed) {
    unsigned short* hs_bf = (unsigned short*)d_ws;                 // 128 MB
    unsigned short* w1_bf = hs_bf + HS_N;                          // 2 MB
    float* fws   = (float*)(w1_bf + W1_N);
    float* e_buf = fws;                     // 65536
    float* tdot  = fws + 65536;             // 32
    float* v     = fws + 65568;             // 2048
    float* c     = fws + 67616;             // 32768

    hipMemsetAsync(e_buf, 0, 65536 * sizeof(float), stream);
    hipMemsetAsync(c, 0, 32768 * sizeof(float), stream);

    hipFuncSetAttribute(reinterpret_cast<const void*>(k2_pipe),
                        hipFuncAttributeMaxDynamicSharedMemorySize, 131072);

    k_conv<<<(int)(HS_N/8/256), 256, 0, stream>>>(h_s, hs_bf, (int)(HS_N/8));
    k_conv<<<(int)(W1_N/8/256), 256, 0, stream>>>(W1, w1_bf, (int)(W1_N/8));
    k0_tdot<<<32, 256, 0, stream>>>(h_t, Wmap, bmap, tdot);
    k1_gate<<<16384, 256, 0, stream>>>(aux, Wmap, noise, tdot, galign);
    k2_pipe<<<1024, 512, 131072, stream>>>(hs_bf, w1_bf, b1, W2, e_buf);
    k3a_vmax<<<8, 256, 0, stream>>>(e_buf, v);
    k3b_align<<<32, 256, 0, stream>>>(e_buf, v, galign);
    k4_ctx_bf16<<<2048, 256, 0, stream>>>(hs_bf, galign, c);
    k5_out<<<8192, 256, 0, stream>>>(c, h_t, Wout, out);
  } else {
    float* ws    = (float*)d_ws;
    float* e_buf = ws;                      // 65536
    float* tdot  = ws + 65536;              // 32
    float* v     = ws + 65568;              // 2048
    float* c     = ws + 67616;              // 32768

    hipMemsetAsync(e_buf, 0, 65536 * sizeof(float), stream);
    hipMemsetAsync(c, 0, 32768 * sizeof(float), stream);

    k0_tdot<<<32, 256, 0, stream>>>(h_t, Wmap, bmap, tdot);
    k1_gate<<<16384, 256, 0, stream>>>(aux, Wmap, noise, tdot, galign);
    k2_egemm_f32<<<4096, 256, 0, stream>>>(h_s, W1, b1, W2, e_buf);
    k3a_vmax<<<8, 256, 0, stream>>>(e_buf, v);
    k3b_align<<<32, 256, 0, stream>>>(e_buf, v, galign);
    k4_ctx_f32<<<2048, 256, 0, stream>>>(h_s, galign, c);
    k5_out<<<8192, 256, 0, stream>>>(c, h_t, Wout, out);
  }
}

// Round 6
// 362.335 us; speedup vs baseline: 1.4803x; 1.0066x over previous
//
#include <hip/hip_runtime.h>
#include <hip/hip_bf16.h>
#include <math.h>

#define B_ 32
#define S_ 2048
#define D_ 1024
#define TEMP_ 9.0f

typedef __attribute__((ext_vector_type(8))) short short8;
typedef __attribute__((ext_vector_type(4))) float f32x4;
typedef __attribute__((ext_vector_type(4))) unsigned short ushort4v;

__device__ __forceinline__ unsigned short f2b(float f) {
  union { float f; unsigned int u; } v; v.f = f;
  unsigned int r = v.u;
  r += 0x7fffu + ((r >> 16) & 1u);   // RNE
  return (unsigned short)(r >> 16);
}
__device__ __forceinline__ float b2f(unsigned short b) {
  union { float f; unsigned int u; } v; v.u = ((unsigned int)b) << 16;
  return v.f;
}
// fast tanh: 1 - 2/(e^2x + 1); saturates correctly at +-inf
__device__ __forceinline__ float tanh_fast(float x) {
  float ez = __expf(2.f * x);
  return 1.f - __fdividef(2.f, ez + 1.f);
}

#define GLOAD_LDS16(g, l) \
  __builtin_amdgcn_global_load_lds((const __attribute__((address_space(1))) void*)(g), \
                                   (__attribute__((address_space(3))) void*)(l), 16, 0, 0)

// ---------------- K_conv: f32 -> bf16, 8 elements/thread ----------------
__global__ void k_conv(const float* __restrict__ src, unsigned short* __restrict__ dst, int n8) {
  int i = blockIdx.x * 256 + threadIdx.x;
  if (i >= n8) return;
  const float4* g = reinterpret_cast<const float4*>(src) + (size_t)i * 2;
  float4 x0 = g[0], x1 = g[1];
  uint4 w;
  w.x = f2b(x0.x) | ((unsigned)f2b(x0.y) << 16);
  w.y = f2b(x0.z) | ((unsigned)f2b(x0.w) << 16);
  w.z = f2b(x1.x) | ((unsigned)f2b(x1.y) << 16);
  w.w = f2b(x1.z) | ((unsigned)f2b(x1.w) << 16);
  reinterpret_cast<uint4*>(dst)[i] = w;
}

// ---------------- K0: tdot[b] = h_t[b]·Wm_t + bmap ----------------
__global__ void k0_tdot(const float* __restrict__ h_t, const float* __restrict__ Wmap,
                        const float* __restrict__ bmap, float* __restrict__ tdot) {
  int b = blockIdx.x;
  int t = threadIdx.x;
  float p = 0.f;
  for (int k = t; k < D_; k += 256) p += h_t[b*D_ + k] * Wmap[D_ + k];
  __shared__ float red[256];
  red[t] = p; __syncthreads();
  for (int off = 128; off > 0; off >>= 1) { if (t < off) red[t] += red[t+off]; __syncthreads(); }
  if (t == 0) tdot[b] = red[0] + bmap[0];
}

// ---------------- K1: G[b,s] = sigmoid((aux·Wm_a + tdot[b] + logistic(u))/T) ----------------
__global__ void k1_gate(const float* __restrict__ aux, const float* __restrict__ Wmap,
                        const float* __restrict__ noise, const float* __restrict__ tdot,
                        float* __restrict__ Gout) {
  int w = (blockIdx.x * 256 + threadIdx.x) >> 6;  // global wave = row index b*S+s
  int lane = threadIdx.x & 63;
  const float4* arow = reinterpret_cast<const float4*>(aux + (size_t)w * D_);
  const float4* wrow = reinterpret_cast<const float4*>(Wmap);
  float p = 0.f;
  for (int it = 0; it < 4; ++it) {
    float4 a = arow[it*64 + lane];
    float4 m = wrow[it*64 + lane];
    p += a.x*m.x + a.y*m.y + a.z*m.z + a.w*m.w;
  }
  for (int msk = 32; msk > 0; msk >>= 1) p += __shfl_xor(p, msk);
  if (lane == 0) {
    int b = w >> 11;
    float logits = p + tdot[b];
    float u = noise[w];
    u = fminf(fmaxf(u, 1e-7f), 1.f - 1e-7f);
    float logistic = logf(u) - log1pf(-u);
    float x = (logits + logistic) / TEMP_;
    Gout[w] = 1.f / (1.f + expf(-x));
  }
}

// ---------------- K2: 256x256 tile, BK=32, quad-buffered depth-3 pipeline ----------------
// e[row] = sum_col tanh(h_s·W1[col,:] + b1[col]) * W2[col]
// T2 swizzle (0 conflicts measured r5): 64B rows, 4 slots of 16B;
// physical slot = logical slot ^ ((r>>1)&3); applied on stage-src and ds-read.
// All addressing hoisted; tile constants folded via full unroll.
#define BK3 32
#define NT3 (D_ / BK3)   // 32 K-tiles

extern __shared__ unsigned short lds2[];  // 4 bufs x (A 256x32 + B 256x32) ushort = 128 KiB

__global__ __launch_bounds__(512, 2) void k2_pipe(
    const unsigned short* __restrict__ Ag, const unsigned short* __restrict__ Bg,
    const float* __restrict__ b1, const float* __restrict__ W2,
    float* __restrict__ e_buf) {
  // T1 bijective XCD swizzle: all 4 col-chunks of a row-chunk on one XCD.
  int hw = blockIdx.x;
  int xcd = hw & 7;
  int sub = hw >> 3;            // [0,128)
  int cc  = sub & 3;
  int rc  = xcd + 8 * (sub >> 2);
  int rowBase = rc * 256;
  int colBase = cc * 256;

  int t = threadIdx.x;
  int lane = t & 63;
  int wv = t >> 6;
  int wr = wv >> 2, wc = wv & 3;   // 2 x 4 wave grid; wave output 128 rows x 64 cols
  int kslot = lane >> 4;           // lane's logical 16B k-slot within a 64B row

  // ---- hoisted ds-read byte offsets (within one 32 KiB buffer) ----
  int aOff[8], bOff[4];
#pragma unroll
  for (int m = 0; m < 8; ++m) {
    int ra = wr * 128 + m * 16 + (lane & 15);
    aOff[m] = ra * 64 + ((kslot ^ ((ra >> 1) & 3)) << 4);
  }
#pragma unroll
  for (int n = 0; n < 4; ++n) {
    int rb = wc * 64 + n * 16 + (lane & 15);
    bOff[n] = 16384 + rb * 64 + ((kslot ^ ((rb >> 1) & 3)) << 4);
  }

  // ---- hoisted stage source bases (k0=0) and LDS dest offsets ----
  const unsigned short* gA[2];
  const unsigned short* gB[2];
  int dstOff[2];
#pragma unroll
  for (int i = 0; i < 2; ++i) {
    int c = i * 512 + t;            // physical chunk [0,1024): r = c/4, slot = c%4
    int r = c >> 2;
    int clog = (c & 3) ^ ((r >> 1) & 3);
    gA[i] = Ag + (size_t)(rowBase + r) * D_ + clog * 8;
    gB[i] = Bg + (size_t)(colBase + r) * D_ + clog * 8;
    dstOff[i] = c * 16;
  }

  f32x4 acc[8][4] = {};

#define STAGE(TT) do {                                                         \
    char* _ba = (char*)lds2 + ((TT) & 3) * 32768;                              \
    GLOAD_LDS16(gA[0] + (TT) * 32, _ba + dstOff[0]);                           \
    GLOAD_LDS16(gA[1] + (TT) * 32, _ba + dstOff[1]);                           \
    GLOAD_LDS16(gB[0] + (TT) * 32, _ba + 16384 + dstOff[0]);                   \
    GLOAD_LDS16(gB[1] + (TT) * 32, _ba + 16384 + dstOff[1]);                   \
  } while (0)

  // Invariants (unchanged from verified r4/r5 kernel):
  //  - lgkmcnt(0) before barrier: buffer (T+3)&3 (read at tile T-1) safe to overwrite.
  //  - vmcnt(VM): VM = 4 loads x tiles-newer-than-T -> tile T's stage landed.
  //  - stage issued after the barrier (memory ops can't cross the asm clobber).
#define K2_TILE(T, VM, DO_STAGE) do {                                          \
    asm volatile("s_waitcnt lgkmcnt(0)\n\ts_waitcnt vmcnt(" #VM ")" ::: "memory"); \
    __builtin_amdgcn_s_barrier();                                              \
    if (DO_STAGE) STAGE((T) + 3);                                              \
    const char* _ab = (const char*)lds2 + ((T) & 3) * 32768;                   \
    short8 af[8], bf[4];                                                       \
    _Pragma("unroll")                                                          \
    for (int n = 0; n < 4; ++n)                                                \
      bf[n] = *reinterpret_cast<const short8*>(_ab + bOff[n]);                 \
    _Pragma("unroll")                                                          \
    for (int m = 0; m < 4; ++m)                                                \
      af[m] = *reinterpret_cast<const short8*>(_ab + aOff[m]);                 \
    __builtin_amdgcn_s_setprio(1);                                             \
    _Pragma("unroll")                                                          \
    for (int m = 0; m < 4; ++m)                                                \
      _Pragma("unroll")                                                        \
      for (int n = 0; n < 4; ++n)                                              \
        acc[m][n] = __builtin_amdgcn_mfma_f32_16x16x32_bf16(af[m], bf[n], acc[m][n], 0, 0, 0); \
    _Pragma("unroll")                                                          \
    for (int m = 4; m < 8; ++m)                                                \
      af[m] = *reinterpret_cast<const short8*>(_ab + aOff[m]);                 \
    _Pragma("unroll")                                                          \
    for (int m = 4; m < 8; ++m)                                                \
      _Pragma("unroll")                                                        \
      for (int n = 0; n < 4; ++n)                                              \
        acc[m][n] = __builtin_amdgcn_mfma_f32_16x16x32_bf16(af[m], bf[n], acc[m][n], 0, 0, 0); \
    __builtin_amdgcn_s_setprio(0);                                             \
  } while (0)

  STAGE(0); STAGE(1); STAGE(2);
#pragma unroll
  for (int tt = 0; tt < 28; ++tt) K2_TILE(tt, 8, true);
  K2_TILE(28, 8, true);    // stages tile 31
  K2_TILE(29, 8, false);
  K2_TILE(30, 4, false);
  K2_TILE(31, 0, false);
#undef K2_TILE
#undef STAGE

  // epilogue: e-partial = sum over this block's 256 cols of tanh(pre+b1)*W2
  float b1v[4], w2v[4];
#pragma unroll
  for (int n = 0; n < 4; ++n) {
    int col = colBase + wc * 64 + n * 16 + (lane & 15);
    b1v[n] = b1[col];
    w2v[n] = W2[col];
  }
#pragma unroll
  for (int m = 0; m < 8; ++m) {
#pragma unroll
    for (int j = 0; j < 4; ++j) {
      float s = 0.f;
#pragma unroll
      for (int n = 0; n < 4; ++n)
        s += tanh_fast(acc[m][n][j] + b1v[n]) * w2v[n];
      s += __shfl_xor(s, 1);
      s += __shfl_xor(s, 2);
      s += __shfl_xor(s, 4);
      s += __shfl_xor(s, 8);
      if ((lane & 15) == 0) {
        int row = rowBase + wr * 128 + m * 16 + ((lane >> 4) << 2) + j;
        atomicAdd(&e_buf[row], s);
      }
    }
  }
}

// ---------------- K2 fallback (f32 inputs, reg-staged conversion, 128^2) ----------------
#define BM 128
#define BN 128
#define BK 64
__global__ __launch_bounds__(256) void k2_egemm_f32(
    const float* __restrict__ h_s, const float* __restrict__ W1,
    const float* __restrict__ b1, const float* __restrict__ W2,
    float* __restrict__ e_buf) {
  __shared__ unsigned short As[BM * BK];
  __shared__ unsigned short Bs[BN * BK];
  int bid = blockIdx.x;
  int colBase = (bid & 7) * BN;
  int rowBase = (bid >> 3) * BM;
  int t = threadIdx.x;
  int lane = t & 63;
  int wave = t >> 6;
  int wr = wave >> 1, wc = wave & 1;
  f32x4 acc[4][4] = {};
  for (int k0 = 0; k0 < D_; k0 += BK) {
    __syncthreads();
    for (int i = 0; i < 4; ++i) {
      int flat = i*256 + t;
      int r = flat >> 3;
      int c8 = flat & 7;
      int byte = (r*128 + c8*16) ^ ((r & 7) << 4);
      {
        const float4* g = reinterpret_cast<const float4*>(h_s + (size_t)(rowBase + r)*D_ + k0 + c8*8);
        float4 x0 = g[0], x1 = g[1];
        uint4 w;
        w.x = f2b(x0.x) | ((unsigned)f2b(x0.y) << 16);
        w.y = f2b(x0.z) | ((unsigned)f2b(x0.w) << 16);
        w.z = f2b(x1.x) | ((unsigned)f2b(x1.y) << 16);
        w.w = f2b(x1.z) | ((unsigned)f2b(x1.w) << 16);
        *reinterpret_cast<uint4*>(reinterpret_cast<char*>(As) + byte) = w;
      }
      {
        const float4* g = reinterpret_cast<const float4*>(W1 + (size_t)(colBase + r)*D_ + k0 + c8*8);
        float4 x0 = g[0], x1 = g[1];
        uint4 w;
        w.x = f2b(x0.x) | ((unsigned)f2b(x0.y) << 16);
        w.y = f2b(x0.z) | ((unsigned)f2b(x0.w) << 16);
        w.z = f2b(x1.x) | ((unsigned)f2b(x1.y) << 16);
        w.w = f2b(x1.z) | ((unsigned)f2b(x1.w) << 16);
        *reinterpret_cast<uint4*>(reinterpret_cast<char*>(Bs) + byte) = w;
      }
    }
    __syncthreads();
    for (int kk = 0; kk < BK; kk += 32) {
      short8 af[4], bf[4];
      int kByte = kk*2 + ((lane >> 4) << 4);
      for (int m = 0; m < 4; ++m) {
        int r = wr*64 + m*16 + (lane & 15);
        int byte = (r*128 + kByte) ^ ((r & 7) << 4);
        af[m] = *reinterpret_cast<const short8*>(reinterpret_cast<const char*>(As) + byte);
      }
      for (int n = 0; n < 4; ++n) {
        int r = wc*64 + n*16 + (lane & 15);
        int byte = (r*128 + kByte) ^ ((r & 7) << 4);
        bf[n] = *reinterpret_cast<const short8*>(reinterpret_cast<const char*>(Bs) + byte);
      }
      for (int m = 0; m < 4; ++m)
        for (int n = 0; n < 4; ++n)
          acc[m][n] = __builtin_amdgcn_mfma_f32_16x16x32_bf16(af[m], bf[n], acc[m][n], 0, 0, 0);
    }
  }
  float b1v[4], w2v[4];
  for (int n = 0; n < 4; ++n) {
    int col = colBase + wc*64 + n*16 + (lane & 15);
    b1v[n] = b1[col];
    w2v[n] = W2[col];
  }
  for (int m = 0; m < 4; ++m) {
    for (int j = 0; j < 4; ++j) {
      float s = 0.f;
      for (int n = 0; n < 4; ++n)
        s += tanhf(acc[m][n][j] + b1v[n]) * w2v[n];
      s += __shfl_xor(s, 1);
      s += __shfl_xor(s, 2);
      s += __shfl_xor(s, 4);
      s += __shfl_xor(s, 8);
      if ((lane & 15) == 0) {
        int row = rowBase + wr*64 + m*16 + ((lane >> 4) << 2) + j;
        atomicAdd(&e_buf[row], s);
      }
    }
  }
}

// ---------------- K3a: v[s] = max_b e[b,s] ----------------
__global__ void k3a_vmax(const float* __restrict__ e_buf, float* __restrict__ v) {
  int s = blockIdx.x * 256 + threadIdx.x;
  if (s >= S_) return;
  float m = -1e30f;
  for (int b = 0; b < B_; ++b) m = fmaxf(m, e_buf[b*S_ + s]);
  v[s] = m;
}

// ---------------- K3b: align = exp(e-v)*G / sum_s (in-place over G) ----------------
__global__ void k3b_align(const float* __restrict__ e_buf, const float* __restrict__ v,
                          float* __restrict__ galign) {
  int b = blockIdx.x;
  int t = threadIdx.x;
  __shared__ float sc[S_];
  __shared__ float red[256];
  float p = 0.f;
  for (int s = t; s < S_; s += 256) {
    float x = expf(e_buf[b*S_ + s] - v[s]) * galign[b*S_ + s];
    sc[s] = x;
    p += x;
  }
  red[t] = p; __syncthreads();
  for (int off = 128; off > 0; off >>= 1) { if (t < off) red[t] += red[t+off]; __syncthreads(); }
  float inv = 1.f / red[0];
  for (int s = t; s < S_; s += 256) galign[b*S_ + s] = sc[s] * inv;
}

// ---------------- K4 (bf16 h_s): c[b,:] = sum_s align[b,s]*h_s[b,s,:] ----------------
__global__ void k4_ctx_bf16(const unsigned short* __restrict__ hsb, const float* __restrict__ align,
                            float* __restrict__ c) {
  int bid = blockIdx.x;
  int b = bid >> 6;
  int sBase = (bid & 63) * 32;
  int t = threadIdx.x;
  float4 accv = {0.f, 0.f, 0.f, 0.f};
  for (int si = 0; si < 32; ++si) {
    int s = sBase + si;
    float a = align[b*S_ + s];
    ushort4v hv = *reinterpret_cast<const ushort4v*>(hsb + (size_t)(b*S_ + s)*D_ + t*4);
    accv.x += a*b2f(hv.x); accv.y += a*b2f(hv.y); accv.z += a*b2f(hv.z); accv.w += a*b2f(hv.w);
  }
  atomicAdd(&c[b*D_ + t*4 + 0], accv.x);
  atomicAdd(&c[b*D_ + t*4 + 1], accv.y);
  atomicAdd(&c[b*D_ + t*4 + 2], accv.z);
  atomicAdd(&c[b*D_ + t*4 + 3], accv.w);
}

// ---------------- K4 fallback (f32 h_s) ----------------
__global__ void k4_ctx_f32(const float* __restrict__ h_s, const float* __restrict__ align,
                           float* __restrict__ c) {
  int bid = blockIdx.x;
  int b = bid >> 6;
  int sBase = (bid & 63) * 32;
  int t = threadIdx.x;
  float4 accv = {0.f, 0.f, 0.f, 0.f};
  for (int si = 0; si < 32; ++si) {
    int s = sBase + si;
    float a = align[b*S_ + s];
    float4 hv = *reinterpret_cast<const float4*>(h_s + (size_t)(b*S_ + s)*D_ + t*4);
    accv.x += a*hv.x; accv.y += a*hv.y; accv.z += a*hv.z; accv.w += a*hv.w;
  }
  atomicAdd(&c[b*D_ + t*4 + 0], accv.x);
  atomicAdd(&c[b*D_ + t*4 + 1], accv.y);
  atomicAdd(&c[b*D_ + t*4 + 2], accv.z);
  atomicAdd(&c[b*D_ + t*4 + 3], accv.w);
}

// ---------------- K5: attn_h = tanh([c,h_t] @ Wout^T) ----------------
__global__ void k5_out(const float* __restrict__ c, const float* __restrict__ h_t,
                       const float* __restrict__ Wout, float* __restrict__ out) {
  int W = (blockIdx.x * 256 + threadIdx.x) >> 6;
  int lane = threadIdx.x & 63;
  int b = W >> 10;
  int o = W & 1023;
  const float* wrow = Wout + (size_t)o * (2 * D_);
  float p = 0.f;
  for (int it = 0; it < 16; ++it) {
    int k = it*64 + lane;
    p += c[b*D_ + k] * wrow[k];
  }
  for (int it = 16; it < 32; ++it) {
    int k = it*64 + lane;
    p += h_t[b*D_ + (k - D_)] * wrow[k];
  }
  for (int m = 32; m > 0; m >>= 1) p += __shfl_xor(p, m);
  if (lane == 0) out[b*D_ + o] = tanhf(p);
}

extern "C" void kernel_launch(void* const* d_in, const int* in_sizes, int n_in,
                              void* d_out, int out_size, void* d_ws, size_t ws_size,
                              hipStream_t stream) {
  const float* h_t   = (const float*)d_in[0];
  const float* h_s   = (const float*)d_in[1];
  const float* aux   = (const float*)d_in[2];
  const float* noise = (const float*)d_in[3];
  const float* Wmap  = (const float*)d_in[4];
  const float* bmap  = (const float*)d_in[5];
  const float* W1    = (const float*)d_in[6];
  const float* b1    = (const float*)d_in[7];
  const float* W2    = (const float*)d_in[8];
  // d_in[9] = b2: cancels exactly in exp(e-v)/sum -> unused
  const float* Wout  = (const float*)d_in[10];

  float* out    = (float*)d_out;          // [attn_h: 32768 | align: 65536]
  float* galign = out + B_*D_;            // holds G first, overwritten with align

  const size_t HS_N   = (size_t)B_*S_*D_;   // 64M
  const size_t W1_N   = (size_t)D_*D_;      // 1M
  const size_t needed = HS_N*2 + W1_N*2 + (65536 + 32 + 2048 + 32768) * sizeof(float);

  if (ws_size >= needed) {
    unsigned short* hs_bf = (unsigned short*)d_ws;                 // 128 MB
    unsigned short* w1_bf = hs_bf + HS_N;                          // 2 MB
    float* fws   = (float*)(w1_bf + W1_N);
    float* e_buf = fws;                     // 65536
    float* tdot  = fws + 65536;             // 32
    float* v     = fws + 65568;             // 2048
    float* c     = fws + 67616;             // 32768

    hipMemsetAsync(e_buf, 0, 65536 * sizeof(float), stream);
    hipMemsetAsync(c, 0, 32768 * sizeof(float), stream);

    hipFuncSetAttribute(reinterpret_cast<const void*>(k2_pipe),
                        hipFuncAttributeMaxDynamicSharedMemorySize, 131072);

    k_conv<<<(int)(HS_N/8/256), 256, 0, stream>>>(h_s, hs_bf, (int)(HS_N/8));
    k_conv<<<(int)(W1_N/8/256), 256, 0, stream>>>(W1, w1_bf, (int)(W1_N/8));
    k0_tdot<<<32, 256, 0, stream>>>(h_t, Wmap, bmap, tdot);
    k1_gate<<<16384, 256, 0, stream>>>(aux, Wmap, noise, tdot, galign);
    k2_pipe<<<1024, 512, 131072, stream>>>(hs_bf, w1_bf, b1, W2, e_buf);
    k3a_vmax<<<8, 256, 0, stream>>>(e_buf, v);
    k3b_align<<<32, 256, 0, stream>>>(e_buf, v, galign);
    k4_ctx_bf16<<<2048, 256, 0, stream>>>(hs_bf, galign, c);
    k5_out<<<8192, 256, 0, stream>>>(c, h_t, Wout, out);
  } else {
    float* ws    = (float*)d_ws;
    float* e_buf = ws;                      // 65536
    float* tdot  = ws + 65536;              // 32
    float* v     = ws + 65568;              // 2048
    float* c     = ws + 67616;              // 32768

    hipMemsetAsync(e_buf, 0, 65536 * sizeof(float), stream);
    hipMemsetAsync(c, 0, 32768 * sizeof(float), stream);

    k0_tdot<<<32, 256, 0, stream>>>(h_t, Wmap, bmap, tdot);
    k1_gate<<<16384, 256, 0, stream>>>(aux, Wmap, noise, tdot, galign);
    k2_egemm_f32<<<4096, 256, 0, stream>>>(h_s, W1, b1, W2, e_buf);
    k3a_vmax<<<8, 256, 0, stream>>>(e_buf, v);
    k3b_align<<<32, 256, 0, stream>>>(e_buf, v, galign);
    k4_ctx_f32<<<2048, 256, 0, stream>>>(h_s, galign, c);
    k5_out<<<8192, 256, 0, stream>>>(c, h_t, Wout, out);
  }
}